// Round 1
// baseline (225.261 us; speedup 1.0000x reference)
//
#include <hip/hip_runtime.h>
#include <math.h>

#define N_B 8
#define PS 6
#define P2 36
#define KK 9
#define CI 32
#define OO 32
#define KC 288   /* KK*CI */
#define EPSF 1e-9f
#define TWO_PI_F 6.2831853071795864769f

/* workspace offsets in floats */
#define RR_OFF   0u
#define ZZ_OFF   2654208u
#define MEAN_OFF 5308416u
#define VAR_OFF  5455872u
#define ACT_OFF  5603328u

__device__ __forceinline__ int covr(int x){
  /* number of parents r in [0,5] with 2r <= x <= 2r+2 */
  int cnt = 0;
#pragma unroll
  for (int r = 0; r < 6; ++r) {
    int i = x - 2*r;
    cnt += (i >= 0 && i <= 2) ? 1 : 0;
  }
  return cnt;
}

/* ---------------- M-step: one block per (n, parent-pos) ---------------- */
template<int IT>
__global__ __launch_bounds__(512) void mstep_kernel(
    const float* __restrict__ inp, const float* __restrict__ w,
    const float* __restrict__ beta_v, const float* __restrict__ beta_a,
    float* __restrict__ ws, float* __restrict__ out)
{
  __shared__ float s_pose[KC*16];
  __shared__ float s_act[KC];
  __shared__ float s_rr[KC*OO];
  __shared__ float s_cost[OO];

  const int blk = blockIdx.x;        /* n*36 + p */
  const int n = blk / P2, p = blk % P2;
  const int pr = p / PS, pc = p % PS;
  const int t = threadIdx.x;

  const float* ibase = inp + (size_t)n * 196 * 32 * 17;

  /* stage pose tile: k = kk*32+ci, 16 pose elems each */
  for (int e = t; e < KC*16; e += 512) {
    int k = e >> 4, h = e & 15;
    int kk = k >> 5, ci = k & 31;
    int i = kk / 3, j = kk % 3;
    int row = pr*2 + i, col = pc*2 + j;
    s_pose[e] = ibase[((row*14 + col)*32 + ci)*17 + h];
  }
  /* stage activations */
  for (int e = t; e < KC; e += 512) {
    int kk = e >> 5, ci = e & 31;
    int i = kk / 3, j = kk % 3;
    int row = pr*2 + i, col = pc*2 + j;
    s_act[e] = ibase[((row*14 + col)*32 + ci)*17 + 16];
  }
  /* stage rr */
  if (IT == 0) {
    for (int e = t; e < KC*OO; e += 512) {
      int k = e >> 5;
      int kk = k >> 5;
      int i = kk / 3, j = kk % 3;
      int ppcv = covr(pr*2 + i) * covr(pc*2 + j);
      s_rr[e] = 1.0f / (float)(ppcv * OO);
    }
  } else {
    const float* rrg = ws + RR_OFF + (size_t)blk * KC * OO;
    for (int e = t; e < KC*OO; e += 512) s_rr[e] = rrg[e];
  }
  __syncthreads();

  const int o = t >> 4, h = t & 15, a = h >> 2, c = h & 3;

  float acc1 = 0.0f, acc2 = 0.0f, srr = 0.0f;
  for (int k = 0; k < KC; ++k) {
    float rrp = s_rr[k*OO + o] * s_act[k];
    const float* wk = w + (((size_t)k*OO + o) << 4);
    const float* pk = s_pose + k*16 + a*4;
    float v = pk[0]*wk[c] + pk[1]*wk[4 + c] + pk[2]*wk[8 + c] + pk[3]*wk[12 + c];
    srr  += rrp;
    acc1 += rrp * v;
    acc2 += rrp * v * v;
  }
  float S    = srr + EPSF;
  float mean = acc1 / S;
  float var  = fmaxf(acc2 / S - mean*mean, 0.0f) + EPSF;

  /* cost over h (16-lane reduce), then act_j via o-reduction in LDS */
  float ch = (beta_v[o] + 0.5f * logf(var)) * srr;
#pragma unroll
  for (int d = 1; d < 16; d <<= 1) ch += __shfl_xor(ch, d, 64);
  if (h == 0) s_cost[o] = ch;
  __syncthreads();

  float cm = 0.0f;
#pragma unroll 8
  for (int oi = 0; oi < OO; ++oi) cm += s_cost[oi];
  cm *= (1.0f / OO);
  float ssq = 0.0f;
#pragma unroll 8
  for (int oi = 0; oi < OO; ++oi) { float d = s_cost[oi] - cm; ssq += d*d; }
  float sd = sqrtf(ssq * (1.0f / OO));

  const float INVT = (IT == 0) ? 0.0005f : ((IT == 1) ? 0.000975f : 0.00142625f);
  float arg = INVT * (beta_a[o] + (cm - s_cost[o]) / (sd + EPSF));
  float aj  = 1.0f / (1.0f + expf(-arg));

  if (IT < 2) {
    ws[MEAN_OFF + ((size_t)blk*OO + o)*16 + h] = mean;
    ws[VAR_OFF  + ((size_t)blk*OO + o)*16 + h] = var;
    if (h == 0) ws[ACT_OFF + (size_t)blk*OO + o] = aj;
  } else {
    float* ob = out + ((size_t)blk*OO + o)*17;
    ob[1 + h] = mean;
    if (h == 0) ob[0] = aj;
  }
}

/* ---------------- E-step part 1: zz = log(act_j+eps) + ln_p ---------------- */
__global__ __launch_bounds__(512) void estep_kernel(
    const float* __restrict__ inp, const float* __restrict__ w,
    float* __restrict__ ws)
{
  __shared__ float s_pose[KC*16];
  __shared__ float s_mean[OO*16];
  __shared__ float s_i2v[OO*16];
  __shared__ float s_ld[OO];
  __shared__ float s_la[OO];

  const int blk = blockIdx.x;
  const int n = blk / P2, p = blk % P2;
  const int pr = p / PS, pc = p % PS;
  const int t = threadIdx.x;

  const float* ibase = inp + (size_t)n * 196 * 32 * 17;
  for (int e = t; e < KC*16; e += 512) {
    int k = e >> 4, h = e & 15;
    int kk = k >> 5, ci = k & 31;
    int i = kk / 3, j = kk % 3;
    int row = pr*2 + i, col = pc*2 + j;
    s_pose[e] = ibase[((row*14 + col)*32 + ci)*17 + h];
  }
  {
    /* t in [0,512) == (o,h) */
    float m = ws[MEAN_OFF + (size_t)blk*OO*16 + t];
    float v = ws[VAR_OFF  + (size_t)blk*OO*16 + t];
    s_mean[t] = m;
    s_i2v[t]  = 0.5f / v;
    float lv = logf(TWO_PI_F * v);
#pragma unroll
    for (int d = 1; d < 16; d <<= 1) lv += __shfl_xor(lv, d, 64);
    if ((t & 15) == 0) s_ld[t >> 4] = lv;
  }
  if (t < OO) s_la[t] = logf(ws[ACT_OFF + (size_t)blk*OO + t] + EPSF);
  __syncthreads();

  float* zz = ws + ZZ_OFF + (size_t)blk * KC * OO;
  for (int e = t; e < KC*OO; e += 512) {
    int k = e >> 5, o = e & 31;
    const float4* wk = (const float4*)(w + (((size_t)k*OO + o) << 4));
    float4 wb0 = wk[0], wb1 = wk[1], wb2 = wk[2], wb3 = wk[3];
    const float* pk = s_pose + k*16;
    const float* mo = s_mean + o*16;
    const float* io = s_i2v + o*16;
    float ssum = 0.0f;
#pragma unroll
    for (int aa = 0; aa < 4; ++aa) {
      float p0 = pk[aa*4+0], p1 = pk[aa*4+1], p2 = pk[aa*4+2], p3 = pk[aa*4+3];
      float vx = p0*wb0.x + p1*wb1.x + p2*wb2.x + p3*wb3.x;
      float vy = p0*wb0.y + p1*wb1.y + p2*wb2.y + p3*wb3.y;
      float vz = p0*wb0.z + p1*wb1.z + p2*wb2.z + p3*wb3.z;
      float vw = p0*wb0.w + p1*wb1.w + p2*wb2.w + p3*wb3.w;
      float d0 = vx - mo[aa*4+0]; ssum += d0*d0*io[aa*4+0];
      float d1 = vy - mo[aa*4+1]; ssum += d1*d1*io[aa*4+1];
      float d2 = vz - mo[aa*4+2]; ssum += d2*d2*io[aa*4+2];
      float d3 = vw - mo[aa*4+3]; ssum += d3*d3*io[aa*4+3];
    }
    zz[e] = s_la[o] - 0.5f * s_ld[o] - ssum;
  }
}

/* ------------- E-step part 2: per-child softmax over parents ------------- */
__global__ __launch_bounds__(256) void childnorm_kernel(float* __restrict__ ws)
{
  const int g = blockIdx.x * 256 + threadIdx.x;   /* 8*169*32 = 43264 total */
  const int n   = g / (169*32);
  const int rem = g % (169*32);
  const int sc  = rem >> 5, ci = rem & 31;
  const int x = sc / 13, y = sc % 13;             /* covered child coords */

  int b0 = -1, b1 = -1, b2 = -1, b3 = -1;
  int np = 0;
#pragma unroll
  for (int r = 0; r < 6; ++r) {
    int i = x - 2*r;
    if (i < 0 || i > 2) continue;
#pragma unroll
    for (int c2 = 0; c2 < 6; ++c2) {
      int j = y - 2*c2;
      if (j < 0 || j > 2) continue;
      int p = r*6 + c2, kk = i*3 + j;
      int base = (((n*P2 + p)*KK + kk)*CI + ci) * OO;
      if (np == 0) b0 = base; else if (np == 1) b1 = base;
      else if (np == 2) b2 = base; else b3 = base;
      ++np;
    }
  }

  const float* zz = ws + ZZ_OFF;
  float m = -1e30f;
  if (b0 >= 0) for (int o = 0; o < 32; ++o) m = fmaxf(m, zz[b0 + o]);
  if (b1 >= 0) for (int o = 0; o < 32; ++o) m = fmaxf(m, zz[b1 + o]);
  if (b2 >= 0) for (int o = 0; o < 32; ++o) m = fmaxf(m, zz[b2 + o]);
  if (b3 >= 0) for (int o = 0; o < 32; ++o) m = fmaxf(m, zz[b3 + o]);

  float den = 0.0f;
  if (b0 >= 0) for (int o = 0; o < 32; ++o) den += expf(zz[b0 + o] - m);
  if (b1 >= 0) for (int o = 0; o < 32; ++o) den += expf(zz[b1 + o] - m);
  if (b2 >= 0) for (int o = 0; o < 32; ++o) den += expf(zz[b2 + o] - m);
  if (b3 >= 0) for (int o = 0; o < 32; ++o) den += expf(zz[b3 + o] - m);

  float inv = 1.0f / (den + EPSF);
  float* rr = ws + RR_OFF;
  if (b0 >= 0) for (int o = 0; o < 32; ++o) rr[b0 + o] = expf(zz[b0 + o] - m) * inv;
  if (b1 >= 0) for (int o = 0; o < 32; ++o) rr[b1 + o] = expf(zz[b1 + o] - m) * inv;
  if (b2 >= 0) for (int o = 0; o < 32; ++o) rr[b2 + o] = expf(zz[b2 + o] - m) * inv;
  if (b3 >= 0) for (int o = 0; o < 32; ++o) rr[b3 + o] = expf(zz[b3 + o] - m) * inv;
}

extern "C" void kernel_launch(void* const* d_in, const int* in_sizes, int n_in,
                              void* d_out, int out_size, void* d_ws, size_t ws_size,
                              hipStream_t stream)
{
  const float* inp = (const float*)d_in[0];
  const float* w   = (const float*)d_in[1];
  const float* bv  = (const float*)d_in[2];
  const float* ba  = (const float*)d_in[3];
  float* out = (float*)d_out;
  float* ws  = (float*)d_ws;

  mstep_kernel<0><<<288, 512, 0, stream>>>(inp, w, bv, ba, ws, out);
  estep_kernel   <<<288, 512, 0, stream>>>(inp, w, ws);
  childnorm_kernel<<<169, 256, 0, stream>>>(ws);
  mstep_kernel<1><<<288, 512, 0, stream>>>(inp, w, bv, ba, ws, out);
  estep_kernel   <<<288, 512, 0, stream>>>(inp, w, ws);
  childnorm_kernel<<<169, 256, 0, stream>>>(ws);
  mstep_kernel<2><<<288, 512, 0, stream>>>(inp, w, bv, ba, ws, out);
}

// Round 2
// 219.942 us; speedup vs baseline: 1.0242x; 1.0242x over previous
//
#include <hip/hip_runtime.h>
#include <math.h>

#define PS 6
#define P2 36
#define KK9 9
#define CI 32
#define OO 32
#define KC 288
#define KCO 9216
#define EPSF 1e-9f
#define LOG2PI_F 1.8378770664093455f

/* workspace offsets in floats */
#define RR_OFF 0u
#define ZZ_OFF 2654208u
#define WT_OFF 5308416u

__device__ __forceinline__ int covr(int x){
  int cnt = 0;
#pragma unroll
  for (int r = 0; r < 6; ++r) { int i = x - 2*r; cnt += (i >= 0 && i <= 2) ? 1 : 0; }
  return cnt;
}

/* transpose w[k][o][b][c] -> wT[k][o][c][b] so a vote column is one float4 */
__global__ __launch_bounds__(256) void wtrans_kernel(const float* __restrict__ w,
                                                     float* __restrict__ wT)
{
  int e = blockIdx.x * 256 + threadIdx.x;   /* 147456 total */
  int ko = e >> 4, bc = e & 15;
  wT[(ko << 4) + ((bc & 3) << 2) + (bc >> 2)] = w[e];
}

/* ---- fused M-step (+E-step zz for IT<2): one block per (n, parent) ---- */
template<int IT>
__global__ __launch_bounds__(512) void emstep_kernel(
    const float* __restrict__ inp, const float* __restrict__ wT,
    const float* __restrict__ beta_v, const float* __restrict__ beta_a,
    float* __restrict__ ws, float* __restrict__ out)
{
  __shared__ float s_pose[KC*16];                   /* 18 KB */
  __shared__ float s_act[(IT == 0) ? KC : 4];
  __shared__ float s_ppci[12];
  __shared__ float s_red[9*512];                    /* 18 KB */
  __shared__ float s_cost[OO];
  __shared__ float s_lv[OO];
  __shared__ float s_mean[(IT < 2) ? 512 : 4];
  __shared__ float s_i2v[(IT < 2) ? 512 : 4];
  __shared__ float s_lc[(IT < 2) ? OO : 4];

  const int blk = blockIdx.x;        /* n*36 + p */
  const int n = blk / P2, p = blk % P2;
  const int pr = p / PS, pc = p % PS;
  const int t = threadIdx.x;

  const float* ibase = inp + (size_t)n * (196*32*17);

  /* stage pose tile */
  for (int e = t; e < KC*16; e += 512) {
    int k = e >> 4, h = e & 15;
    int kk = k >> 5, ci = k & 31;
    int i = kk / 3, j = kk % 3;
    s_pose[e] = ibase[(((pr*2+i)*14 + (pc*2+j))*32 + ci)*17 + h];
  }
  if (IT == 0) {
    if (t < KC) {
      int kk = t >> 5, ci = t & 31;
      int i = kk / 3, j = kk % 3;
      s_act[t] = ibase[(((pr*2+i)*14 + (pc*2+j))*32 + ci)*17 + 16];
    }
    if (t < 9) {
      int i = t / 3, j = t % 3;
      s_ppci[t] = 1.0f / (float)(covr(pr*2+i) * covr(pc*2+j) * OO);
    }
  }
  __syncthreads();

  const int k4 = t >> 7;          /* 0..3 : k-split group */
  const int oa = t & 127;
  const int o  = oa >> 2, a = oa & 3;

  float srr = 0.f;
  float4 acc1 = {0.f,0.f,0.f,0.f}, acc2 = {0.f,0.f,0.f,0.f};
  {
    const float* wp  = wT + (o << 4);
    const float* pp  = s_pose + (a << 2);
    const float* rrg = ws + RR_OFF + (size_t)blk * KCO + o;
    const int k0 = k4 * 72, k1 = k0 + 72;
#pragma unroll 4
    for (int k = k0; k < k1; ++k) {
      float rra;
      if (IT == 0) rra = s_act[k] * s_ppci[k >> 5];
      else         rra = rrg[(size_t)k << 5];      /* childnorm pre-multiplied act */
      float4 pk = *(const float4*)(pp + (k << 4));
      const float4* wq = (const float4*)(wp + (k << 9));
      float4 w0 = wq[0], w1 = wq[1], w2 = wq[2], w3 = wq[3];
      float v0 = pk.x*w0.x + pk.y*w0.y + pk.z*w0.z + pk.w*w0.w;
      float v1 = pk.x*w1.x + pk.y*w1.y + pk.z*w1.z + pk.w*w1.w;
      float v2 = pk.x*w2.x + pk.y*w2.y + pk.z*w2.z + pk.w*w2.w;
      float v3 = pk.x*w3.x + pk.y*w3.y + pk.z*w3.z + pk.w*w3.w;
      srr += rra;
      float r0 = rra*v0, r1 = rra*v1, r2 = rra*v2, r3 = rra*v3;
      acc1.x += r0;    acc1.y += r1;    acc1.z += r2;    acc1.w += r3;
      acc2.x += r0*v0; acc2.y += r1*v1; acc2.z += r2*v2; acc2.w += r3*v3;
    }
  }
  s_red[t]        = srr;
  s_red[512 + t]  = acc1.x;  s_red[1024 + t] = acc1.y;
  s_red[1536 + t] = acc1.z;  s_red[2048 + t] = acc1.w;
  s_red[2560 + t] = acc2.x;  s_red[3072 + t] = acc2.y;
  s_red[3584 + t] = acc2.z;  s_red[4096 + t] = acc2.w;
  __syncthreads();

  float rs = 0.f, a1x=0.f,a1y=0.f,a1z=0.f,a1w=0.f, a2x=0.f,a2y=0.f,a2z=0.f,a2w=0.f;
#pragma unroll
  for (int g = 0; g < 4; ++g) {
    int idx = g*128 + oa;
    rs  += s_red[idx];
    a1x += s_red[512+idx];  a1y += s_red[1024+idx];
    a1z += s_red[1536+idx]; a1w += s_red[2048+idx];
    a2x += s_red[2560+idx]; a2y += s_red[3072+idx];
    a2z += s_red[3584+idx]; a2w += s_red[4096+idx];
  }
  float S  = rs + EPSF;
  float m0 = a1x/S, m1 = a1y/S, m2 = a1z/S, m3 = a1w/S;
  float v0 = fmaxf(a2x/S - m0*m0, 0.f) + EPSF;
  float v1 = fmaxf(a2y/S - m1*m1, 0.f) + EPSF;
  float v2 = fmaxf(a2z/S - m2*m2, 0.f) + EPSF;
  float v3 = fmaxf(a2w/S - m3*m3, 0.f) + EPSF;
  float lsum = __logf(v0) + __logf(v1) + __logf(v2) + __logf(v3);
  float bvo  = beta_v[o];
  float ch   = rs * (4.f*bvo + 0.5f*lsum);
  ch += __shfl_xor(ch, 1, 64);
  ch += __shfl_xor(ch, 2, 64);
  float lvp = lsum;
  lvp += __shfl_xor(lvp, 1, 64);
  lvp += __shfl_xor(lvp, 2, 64);
  if (k4 == 0 && a == 0) { s_cost[o] = ch; s_lv[o] = lvp + 16.f*LOG2PI_F; }
  if (k4 == 0 && IT < 2) {
    float* sm = s_mean + (o<<4) + (a<<2);
    sm[0]=m0; sm[1]=m1; sm[2]=m2; sm[3]=m3;
    float* si = s_i2v + (o<<4) + (a<<2);
    si[0]=0.5f/v0; si[1]=0.5f/v1; si[2]=0.5f/v2; si[3]=0.5f/v3;
  }
  if (k4 == 0 && IT == 2) {
    float* ob = out + ((size_t)blk*OO + o)*17 + 1 + (a<<2);
    ob[0]=m0; ob[1]=m1; ob[2]=m2; ob[3]=m3;
  }
  __syncthreads();

  if (t < OO) {
    float cm = 0.f;
#pragma unroll
    for (int oi = 0; oi < OO; ++oi) cm += s_cost[oi];
    cm *= (1.f/OO);
    float ssq = 0.f;
#pragma unroll
    for (int oi = 0; oi < OO; ++oi) { float d = s_cost[oi]-cm; ssq += d*d; }
    float sd = sqrtf(ssq * (1.f/OO));
    const float INVT = (IT==0) ? 5.0e-4f : ((IT==1) ? 9.75e-4f : 1.42625e-3f);
    float arg = INVT * (beta_a[t] + (cm - s_cost[t]) / (sd + EPSF));
    float aj  = 1.f / (1.f + __expf(-arg));
    if (IT == 2) out[((size_t)blk*OO + t)*17] = aj;
    else         s_lc[t] = __logf(aj + EPSF) - 0.5f * s_lv[t];
  }
  if (IT == 2) return;
  __syncthreads();

  /* ---- fused E-step: zz[k][o] for this (n,p) ---- */
  const int o2 = t & 31;                    /* invariant across the e-loop */
  const float lc = s_lc[o2];
  const float4* mo4 = (const float4*)(s_mean + (o2<<4));
  const float4* io4 = (const float4*)(s_i2v  + (o2<<4));
  float4 M0=mo4[0], M1=mo4[1], M2=mo4[2], M3=mo4[3];
  float4 I0=io4[0], I1=io4[1], I2=io4[2], I3=io4[3];
  float* zz = ws + ZZ_OFF + (size_t)blk * KCO;
  for (int e = t; e < KCO; e += 512) {
    int k = e >> 5;
    const float4* wq = (const float4*)(wT + ((size_t)e << 4));
    float4 w0=wq[0], w1=wq[1], w2=wq[2], w3=wq[3];
    const float4* pk4 = (const float4*)(s_pose + (k << 4));
    float ssum = 0.f;
    {
      float4 P = pk4[0];
      float x0 = P.x*w0.x + P.y*w0.y + P.z*w0.z + P.w*w0.w;
      float x1 = P.x*w1.x + P.y*w1.y + P.z*w1.z + P.w*w1.w;
      float x2 = P.x*w2.x + P.y*w2.y + P.z*w2.z + P.w*w2.w;
      float x3 = P.x*w3.x + P.y*w3.y + P.z*w3.z + P.w*w3.w;
      float d0=x0-M0.x, d1=x1-M0.y, d2=x2-M0.z, d3=x3-M0.w;
      ssum += d0*d0*I0.x + d1*d1*I0.y + d2*d2*I0.z + d3*d3*I0.w;
    }
    {
      float4 P = pk4[1];
      float x0 = P.x*w0.x + P.y*w0.y + P.z*w0.z + P.w*w0.w;
      float x1 = P.x*w1.x + P.y*w1.y + P.z*w1.z + P.w*w1.w;
      float x2 = P.x*w2.x + P.y*w2.y + P.z*w2.z + P.w*w2.w;
      float x3 = P.x*w3.x + P.y*w3.y + P.z*w3.z + P.w*w3.w;
      float d0=x0-M1.x, d1=x1-M1.y, d2=x2-M1.z, d3=x3-M1.w;
      ssum += d0*d0*I1.x + d1*d1*I1.y + d2*d2*I1.z + d3*d3*I1.w;
    }
    {
      float4 P = pk4[2];
      float x0 = P.x*w0.x + P.y*w0.y + P.z*w0.z + P.w*w0.w;
      float x1 = P.x*w1.x + P.y*w1.y + P.z*w1.z + P.w*w1.w;
      float x2 = P.x*w2.x + P.y*w2.y + P.z*w2.z + P.w*w2.w;
      float x3 = P.x*w3.x + P.y*w3.y + P.z*w3.z + P.w*w3.w;
      float d0=x0-M2.x, d1=x1-M2.y, d2=x2-M2.z, d3=x3-M2.w;
      ssum += d0*d0*I2.x + d1*d1*I2.y + d2*d2*I2.z + d3*d3*I2.w;
    }
    {
      float4 P = pk4[3];
      float x0 = P.x*w0.x + P.y*w0.y + P.z*w0.z + P.w*w0.w;
      float x1 = P.x*w1.x + P.y*w1.y + P.z*w1.z + P.w*w1.w;
      float x2 = P.x*w2.x + P.y*w2.y + P.z*w2.z + P.w*w2.w;
      float x3 = P.x*w3.x + P.y*w3.y + P.z*w3.z + P.w*w3.w;
      float d0=x0-M3.x, d1=x1-M3.y, d2=x2-M3.z, d3=x3-M3.w;
      ssum += d0*d0*I3.x + d1*d1*I3.y + d2*d2*I3.z + d3*d3*I3.w;
    }
    zz[e] = lc - ssum;
  }
}

/* ------------- per-child softmax over parents; writes rr*act ------------- */
__device__ __forceinline__ float max8(const float* p, float m){
  const float4* z4 = (const float4*)p;
#pragma unroll
  for (int q=0;q<8;++q){ float4 v=z4[q]; m=fmaxf(m,fmaxf(fmaxf(v.x,v.y),fmaxf(v.z,v.w))); }
  return m;
}
__device__ __forceinline__ float expstore(const float* zp, float* rp, float m, float den){
  const float4* z4=(const float4*)zp; float4* r4=(float4*)rp;
#pragma unroll
  for(int q=0;q<8;++q){ float4 v=z4[q]; float4 e;
    e.x=__expf(v.x-m); e.y=__expf(v.y-m); e.z=__expf(v.z-m); e.w=__expf(v.w-m);
    den += e.x+e.y+e.z+e.w; r4[q]=e; }
  return den;
}
__device__ __forceinline__ void scale8(float* rp, float s){
  float4* r4=(float4*)rp;
#pragma unroll
  for(int q=0;q<8;++q){ float4 e=r4[q]; e.x*=s;e.y*=s;e.z*=s;e.w*=s; r4[q]=e; }
}

__global__ __launch_bounds__(256) void childnorm_kernel(
    const float* __restrict__ inp, float* __restrict__ ws)
{
  const int g = blockIdx.x * 256 + threadIdx.x;   /* 8*169*32 = 43264 */
  const int n   = g / (169*32);
  const int rem = g % (169*32);
  const int sc  = rem >> 5, ci = rem & 31;
  const int x = sc / 13, y = sc % 13;

  const float act = inp[(((size_t)n*196 + x*14 + y)*32 + ci)*17 + 16];

  int b0=-1,b1=-1,b2=-1,b3=-1; int np=0;
#pragma unroll
  for (int r = 0; r < 6; ++r) {
    int i = x - 2*r;
    if (i < 0 || i > 2) continue;
#pragma unroll
    for (int c2 = 0; c2 < 6; ++c2) {
      int j = y - 2*c2;
      if (j < 0 || j > 2) continue;
      int base = (((n*P2 + r*6+c2)*KK9 + i*3+j)*CI + ci) << 5;
      if (np==0) b0=base; else if (np==1) b1=base; else if (np==2) b2=base; else b3=base;
      ++np;
    }
  }
  const float* zz = ws + ZZ_OFF;
  float* rr = ws + RR_OFF;
  float m = -1e30f;
  if (b0>=0) m = max8(zz+b0, m);
  if (b1>=0) m = max8(zz+b1, m);
  if (b2>=0) m = max8(zz+b2, m);
  if (b3>=0) m = max8(zz+b3, m);
  float den = 0.f;
  if (b0>=0) den = expstore(zz+b0, rr+b0, m, den);
  if (b1>=0) den = expstore(zz+b1, rr+b1, m, den);
  if (b2>=0) den = expstore(zz+b2, rr+b2, m, den);
  if (b3>=0) den = expstore(zz+b3, rr+b3, m, den);
  float s = act / (den + EPSF);
  if (b0>=0) scale8(rr+b0, s);
  if (b1>=0) scale8(rr+b1, s);
  if (b2>=0) scale8(rr+b2, s);
  if (b3>=0) scale8(rr+b3, s);
}

extern "C" void kernel_launch(void* const* d_in, const int* in_sizes, int n_in,
                              void* d_out, int out_size, void* d_ws, size_t ws_size,
                              hipStream_t stream)
{
  (void)in_sizes; (void)n_in; (void)out_size; (void)ws_size;
  const float* inp = (const float*)d_in[0];
  const float* w   = (const float*)d_in[1];
  const float* bv  = (const float*)d_in[2];
  const float* ba  = (const float*)d_in[3];
  float* out = (float*)d_out;
  float* ws  = (float*)d_ws;
  float* wT  = ws + WT_OFF;

  wtrans_kernel<<<576, 256, 0, stream>>>(w, wT);
  emstep_kernel<0><<<288, 512, 0, stream>>>(inp, wT, bv, ba, ws, out);
  childnorm_kernel<<<169, 256, 0, stream>>>(inp, ws);
  emstep_kernel<1><<<288, 512, 0, stream>>>(inp, wT, bv, ba, ws, out);
  childnorm_kernel<<<169, 256, 0, stream>>>(inp, ws);
  emstep_kernel<2><<<288, 512, 0, stream>>>(inp, wT, bv, ba, ws, out);
}

// Round 3
// 192.017 us; speedup vs baseline: 1.1731x; 1.1454x over previous
//
#include <hip/hip_runtime.h>
#include <math.h>

#define PS 6
#define P2 36
#define CI 32
#define OO 32
#define KC 288
#define KCO 9216
#define EPSF 1e-9f
#define LOG2PI_F 1.8378770664093455f

/* workspace float offsets */
#define RR_OFF   0u
#define ZZ_OFF   2654208u      /* PART aliases this region (stream-ordered) */
#define PART_OFF 2654208u
#define WT_OFF   5308416u
#define MEAN_OFF 5455872u
#define I2V_OFF  5603328u
#define LC_OFF   5750784u

__device__ __forceinline__ int covr(int x){
  int cnt = 0;
#pragma unroll
  for (int r = 0; r < 6; ++r) { int i = x - 2*r; cnt += (i >= 0 && i <= 2) ? 1 : 0; }
  return cnt;
}

/* w[k][o][b][c] -> wT[k][o][c][b] */
__global__ __launch_bounds__(256) void wtrans_kernel(const float* __restrict__ w,
                                                     float* __restrict__ wT)
{
  int e = blockIdx.x * 256 + threadIdx.x;
  int ko = e >> 4, bc = e & 15;
  wT[(ko << 4) + ((bc & 3) << 2) + (bc >> 2)] = w[e];
}

/* ---- K1: partial moments. grid = 288np * 4k4, block 512 = (o,h) ---- */
template<bool FIRST>
__global__ __launch_bounds__(512, 4) void moments_kernel(
    const float* __restrict__ inp, const float* __restrict__ wT,
    const float* __restrict__ ws_rr, float* __restrict__ part)
{
  __shared__ float s_pose[72*16];
  __shared__ float s_ra[FIRST ? 72 : 4];

  const int blk = blockIdx.x;
  const int np = blk >> 2, k4 = blk & 3;
  const int n = np / P2, p = np % P2;
  const int pr = p / PS, pc = p % PS;
  const int t = threadIdx.x;
  const int k0 = k4 * 72;

  const float* ibase = inp + (size_t)n * (196*32*17);
  for (int e = t; e < 72*16; e += 512) {
    int k = k0 + (e >> 4), h = e & 15;
    int kk = k >> 5, ci = k & 31;
    s_pose[e] = ibase[(((pr*2 + kk/3)*14 + (pc*2 + kk%3))*32 + ci)*17 + h];
  }
  if (FIRST && t < 72) {
    int k = k0 + t; int kk = k >> 5, ci = k & 31;
    int i = kk/3, j = kk%3;
    float a = ibase[(((pr*2+i)*14 + (pc*2+j))*32 + ci)*17 + 16];
    s_ra[t] = a / (float)(covr(pr*2+i) * covr(pc*2+j) * OO);
  }
  __syncthreads();

  const int o = t >> 4, h = t & 15, a = h >> 2, c = h & 3;
  const float* wp = wT + (o << 4) + (c << 2) + ((size_t)k0 << 9);
  const float* pp = s_pose + (a << 2);
  const float* rp = ws_rr + (size_t)np * KCO + ((size_t)k0 << 5) + o;

  float srr = 0.f, m1 = 0.f, m2 = 0.f;
#pragma unroll 8
  for (int k = 0; k < 72; ++k) {
    float rra = FIRST ? s_ra[k] : rp[(size_t)k << 5];
    float4 w4 = *(const float4*)(wp + ((size_t)k << 9));
    float4 p4 = *(const float4*)(pp + (k << 4));
    float v = p4.x*w4.x + p4.y*w4.y + p4.z*w4.z + p4.w*w4.w;
    srr += rra;
    float rv = rra * v;
    m1 += rv; m2 += rv * v;
  }
  float* pb = part + (size_t)blk * 1536 + t;
  pb[0] = srr; pb[512] = m1; pb[1024] = m2;
}

/* ---- K2: combine partials, cost, act_j; emit mean/i2v/lc or output ---- */
template<int IT>
__global__ __launch_bounds__(512) void stats_kernel(
    const float* __restrict__ part,
    const float* __restrict__ beta_v, const float* __restrict__ beta_a,
    float* __restrict__ ws, float* __restrict__ out)
{
  __shared__ float s_cost[OO];
  __shared__ float s_lvs[OO];
  const int np = blockIdx.x;
  const int t = threadIdx.x;
  const int o = t >> 4, h = t & 15;

  float rs = 0.f, a1 = 0.f, a2 = 0.f;
#pragma unroll
  for (int g = 0; g < 4; ++g) {
    const float* pb = part + (size_t)(np*4 + g) * 1536 + t;
    rs += pb[0]; a1 += pb[512]; a2 += pb[1024];
  }
  float S = rs + EPSF;
  float mean = a1 / S;
  float var  = fmaxf(a2 / S - mean*mean, 0.f) + EPSF;
  float lvh  = __logf(var);
  float ch   = (beta_v[o] + 0.5f * lvh) * rs;
  float lv   = lvh;
#pragma unroll
  for (int d = 1; d < 16; d <<= 1) {
    ch += __shfl_xor(ch, d, 64);
    lv += __shfl_xor(lv, d, 64);
  }
  if (h == 0) { s_cost[o] = ch; s_lvs[o] = lv; }
  __syncthreads();

  float cm = 0.f;
#pragma unroll
  for (int oi = 0; oi < OO; ++oi) cm += s_cost[oi];
  cm *= (1.f / OO);
  float ssq = 0.f;
#pragma unroll
  for (int oi = 0; oi < OO; ++oi) { float d = s_cost[oi] - cm; ssq += d*d; }
  float sd = sqrtf(ssq * (1.f / OO));
  const float INVT = (IT==0) ? 5.0e-4f : ((IT==1) ? 9.75e-4f : 1.42625e-3f);
  float arg = INVT * (beta_a[o] + (cm - s_cost[o]) / (sd + EPSF));
  float aj  = 1.f / (1.f + __expf(-arg));

  if (IT == 2) {
    out[((size_t)np*OO + o)*17 + 1 + h] = mean;
    if (h == 0) out[((size_t)np*OO + o)*17] = aj;
  } else {
    ws[MEAN_OFF + (size_t)np*512 + t] = mean;
    ws[I2V_OFF  + (size_t)np*512 + t] = 0.5f / var;
    if (h == 0)
      ws[LC_OFF + (size_t)np*OO + o] =
        __logf(aj + EPSF) - 0.5f * (s_lvs[o] + 16.f * LOG2PI_F);
  }
}

/* ---- K3: zz. grid = 288np * 4k4, block 512 ---- */
__global__ __launch_bounds__(512, 4) void zz_kernel(
    const float* __restrict__ inp, const float* __restrict__ wT,
    float* __restrict__ ws)
{
  __shared__ float s_pose[72*16];
  const int blk = blockIdx.x;
  const int np = blk >> 2, k4 = blk & 3;
  const int n = np / P2, p = np % P2;
  const int pr = p / PS, pc = p % PS;
  const int t = threadIdx.x;
  const int k0 = k4 * 72;

  const float* ibase = inp + (size_t)n * (196*32*17);
  for (int e = t; e < 72*16; e += 512) {
    int k = k0 + (e >> 4), h = e & 15;
    int kk = k >> 5, ci = k & 31;
    s_pose[e] = ibase[(((pr*2 + kk/3)*14 + (pc*2 + kk%3))*32 + ci)*17 + h];
  }
  __syncthreads();

  const int o = t & 31;
  const float lc = ws[LC_OFF + (size_t)np*OO + o];
  const float4* mo4 = (const float4*)(ws + MEAN_OFF + (size_t)np*512 + (o<<4));
  const float4* io4 = (const float4*)(ws + I2V_OFF  + (size_t)np*512 + (o<<4));
  float4 M0=mo4[0], M1=mo4[1], M2=mo4[2], M3=mo4[3];
  float4 I0=io4[0], I1=io4[1], I2=io4[2], I3=io4[3];

  float* zz = ws + ZZ_OFF + (size_t)np * KCO + ((size_t)k0 << 5);
#pragma unroll
  for (int it8 = 0; it8 < 5; ++it8) {
    int e = t + it8*512;
    if (e >= 2304) break;
    int k = e >> 5;                         /* local k */
    const float4* wq = (const float4*)(wT + (((size_t)(k0 + k) << 5) + o) * 16);
    float4 w0=wq[0], w1=wq[1], w2=wq[2], w3=wq[3];
    const float4* pk4 = (const float4*)(s_pose + (k << 4));
    float4 Pa;
    float ssum = 0.f;
    Pa = pk4[0];
    {
      float x0 = Pa.x*w0.x + Pa.y*w0.y + Pa.z*w0.z + Pa.w*w0.w;
      float x1 = Pa.x*w1.x + Pa.y*w1.y + Pa.z*w1.z + Pa.w*w1.w;
      float x2 = Pa.x*w2.x + Pa.y*w2.y + Pa.z*w2.z + Pa.w*w2.w;
      float x3 = Pa.x*w3.x + Pa.y*w3.y + Pa.z*w3.z + Pa.w*w3.w;
      float d0=x0-M0.x, d1=x1-M0.y, d2=x2-M0.z, d3=x3-M0.w;
      ssum += d0*d0*I0.x + d1*d1*I0.y + d2*d2*I0.z + d3*d3*I0.w;
    }
    Pa = pk4[1];
    {
      float x0 = Pa.x*w0.x + Pa.y*w0.y + Pa.z*w0.z + Pa.w*w0.w;
      float x1 = Pa.x*w1.x + Pa.y*w1.y + Pa.z*w1.z + Pa.w*w1.w;
      float x2 = Pa.x*w2.x + Pa.y*w2.y + Pa.z*w2.z + Pa.w*w2.w;
      float x3 = Pa.x*w3.x + Pa.y*w3.y + Pa.z*w3.z + Pa.w*w3.w;
      float d0=x0-M1.x, d1=x1-M1.y, d2=x2-M1.z, d3=x3-M1.w;
      ssum += d0*d0*I1.x + d1*d1*I1.y + d2*d2*I1.z + d3*d3*I1.w;
    }
    Pa = pk4[2];
    {
      float x0 = Pa.x*w0.x + Pa.y*w0.y + Pa.z*w0.z + Pa.w*w0.w;
      float x1 = Pa.x*w1.x + Pa.y*w1.y + Pa.z*w1.z + Pa.w*w1.w;
      float x2 = Pa.x*w2.x + Pa.y*w2.y + Pa.z*w2.z + Pa.w*w2.w;
      float x3 = Pa.x*w3.x + Pa.y*w3.y + Pa.z*w3.z + Pa.w*w3.w;
      float d0=x0-M2.x, d1=x1-M2.y, d2=x2-M2.z, d3=x3-M2.w;
      ssum += d0*d0*I2.x + d1*d1*I2.y + d2*d2*I2.z + d3*d3*I2.w;
    }
    Pa = pk4[3];
    {
      float x0 = Pa.x*w0.x + Pa.y*w0.y + Pa.z*w0.z + Pa.w*w0.w;
      float x1 = Pa.x*w1.x + Pa.y*w1.y + Pa.z*w1.z + Pa.w*w1.w;
      float x2 = Pa.x*w2.x + Pa.y*w2.y + Pa.z*w2.z + Pa.w*w2.w;
      float x3 = Pa.x*w3.x + Pa.y*w3.y + Pa.z*w3.z + Pa.w*w3.w;
      float d0=x0-M3.x, d1=x1-M3.y, d2=x2-M3.z, d3=x3-M3.w;
      ssum += d0*d0*I3.x + d1*d1*I3.y + d2*d2*I3.z + d3*d3*I3.w;
    }
    zz[e] = lc - ssum;
  }
}

/* ---- childnorm: per-child softmax over parents; writes rr*act ---- */
__device__ __forceinline__ float max8(const float* p, float m){
  const float4* z4 = (const float4*)p;
#pragma unroll
  for (int q=0;q<8;++q){ float4 v=z4[q]; m=fmaxf(m,fmaxf(fmaxf(v.x,v.y),fmaxf(v.z,v.w))); }
  return m;
}
__device__ __forceinline__ float expstore(const float* zp, float* rp, float m, float den){
  const float4* z4=(const float4*)zp; float4* r4=(float4*)rp;
#pragma unroll
  for(int q=0;q<8;++q){ float4 v=z4[q]; float4 e;
    e.x=__expf(v.x-m); e.y=__expf(v.y-m); e.z=__expf(v.z-m); e.w=__expf(v.w-m);
    den += e.x+e.y+e.z+e.w; r4[q]=e; }
  return den;
}
__device__ __forceinline__ void scale8(float* rp, float s){
  float4* r4=(float4*)rp;
#pragma unroll
  for(int q=0;q<8;++q){ float4 e=r4[q]; e.x*=s;e.y*=s;e.z*=s;e.w*=s; r4[q]=e; }
}

__global__ __launch_bounds__(256) void childnorm_kernel(
    const float* __restrict__ inp, float* __restrict__ ws)
{
  const int g = blockIdx.x * 256 + threadIdx.x;
  const int n   = g / (169*32);
  const int rem = g % (169*32);
  const int sc  = rem >> 5, ci = rem & 31;
  const int x = sc / 13, y = sc % 13;

  const float act = inp[(((size_t)n*196 + x*14 + y)*32 + ci)*17 + 16];

  int b0=-1,b1=-1,b2=-1,b3=-1; int np2=0;
#pragma unroll
  for (int r = 0; r < 6; ++r) {
    int i = x - 2*r;
    if (i < 0 || i > 2) continue;
#pragma unroll
    for (int c2 = 0; c2 < 6; ++c2) {
      int j = y - 2*c2;
      if (j < 0 || j > 2) continue;
      int base = (((n*P2 + r*6+c2)*9 + i*3+j)*CI + ci) << 5;
      if (np2==0) b0=base; else if (np2==1) b1=base; else if (np2==2) b2=base; else b3=base;
      ++np2;
    }
  }
  const float* zz = ws + ZZ_OFF;
  float* rr = ws + RR_OFF;
  float m = -1e30f;
  if (b0>=0) m = max8(zz+b0, m);
  if (b1>=0) m = max8(zz+b1, m);
  if (b2>=0) m = max8(zz+b2, m);
  if (b3>=0) m = max8(zz+b3, m);
  float den = 0.f;
  if (b0>=0) den = expstore(zz+b0, rr+b0, m, den);
  if (b1>=0) den = expstore(zz+b1, rr+b1, m, den);
  if (b2>=0) den = expstore(zz+b2, rr+b2, m, den);
  if (b3>=0) den = expstore(zz+b3, rr+b3, m, den);
  float s = act / (den + EPSF);
  if (b0>=0) scale8(rr+b0, s);
  if (b1>=0) scale8(rr+b1, s);
  if (b2>=0) scale8(rr+b2, s);
  if (b3>=0) scale8(rr+b3, s);
}

extern "C" void kernel_launch(void* const* d_in, const int* in_sizes, int n_in,
                              void* d_out, int out_size, void* d_ws, size_t ws_size,
                              hipStream_t stream)
{
  (void)in_sizes; (void)n_in; (void)out_size; (void)ws_size;
  const float* inp = (const float*)d_in[0];
  const float* w   = (const float*)d_in[1];
  const float* bv  = (const float*)d_in[2];
  const float* ba  = (const float*)d_in[3];
  float* out = (float*)d_out;
  float* ws  = (float*)d_ws;
  float* wT   = ws + WT_OFF;
  float* part = ws + PART_OFF;
  const float* rr = ws + RR_OFF;

  wtrans_kernel<<<576, 256, 0, stream>>>(w, wT);

  moments_kernel<true ><<<1152, 512, 0, stream>>>(inp, wT, rr, part);
  stats_kernel<0><<<288, 512, 0, stream>>>(part, bv, ba, ws, out);
  zz_kernel<<<1152, 512, 0, stream>>>(inp, wT, ws);
  childnorm_kernel<<<169, 256, 0, stream>>>(inp, ws);

  moments_kernel<false><<<1152, 512, 0, stream>>>(inp, wT, rr, part);
  stats_kernel<1><<<288, 512, 0, stream>>>(part, bv, ba, ws, out);
  zz_kernel<<<1152, 512, 0, stream>>>(inp, wT, ws);
  childnorm_kernel<<<169, 256, 0, stream>>>(inp, ws);

  moments_kernel<false><<<1152, 512, 0, stream>>>(inp, wT, rr, part);
  stats_kernel<2><<<288, 512, 0, stream>>>(part, bv, ba, ws, out);
}

// Round 4
// 159.961 us; speedup vs baseline: 1.4082x; 1.2004x over previous
//
#include <hip/hip_runtime.h>
#include <math.h>

#define PS 6
#define P2 36
#define CI 32
#define OO 32
#define KC 288
#define KCO 9216
#define EPSF 1e-9f
#define LOG2PI_F 1.8378770664093455f

/* workspace float offsets */
#define ZZ_OFF   0u            /* 2,654,208 floats */
#define PART_OFF 2654208u      /* 1,769,472 floats */
#define WT_OFF   4423680u      /* 147,456 floats */
#define MS_OFF   4571136u      /* 43,264 float2 = 86,528 floats */

__device__ __forceinline__ int covr(int x){
  int cnt = 0;
#pragma unroll
  for (int r = 0; r < 6; ++r) { int i = x - 2*r; cnt += (i >= 0 && i <= 2) ? 1 : 0; }
  return cnt;
}

/* w[k][o][b][c] -> wT[k][o][c][b] */
__global__ __launch_bounds__(256) void wtrans_kernel(const float* __restrict__ w,
                                                     float* __restrict__ wT)
{
  int e = blockIdx.x * 256 + threadIdx.x;
  int ko = e >> 4, bc = e & 15;
  wT[(ko << 4) + ((bc & 3) << 2) + (bc >> 2)] = w[e];
}

/* ---- K1: partial moments. grid = 288np * 4k4, block 512 = (o,h) ---- */
template<bool FIRST>
__global__ __launch_bounds__(512, 4) void moments_kernel(
    const float* __restrict__ inp, const float* __restrict__ wT,
    const float* __restrict__ zzg, const float2* __restrict__ msg,
    float* __restrict__ part)
{
  __shared__ float s_pose[72*16];
  __shared__ float s_ra[72];     /* FIRST: rr0*act ; else m */
  __shared__ float s_s[FIRST ? 4 : 72];

  const int blk = blockIdx.x;
  const int np = blk >> 2, k4 = blk & 3;
  const int n = np / P2, p = np % P2;
  const int pr = p / PS, pc = p % PS;
  const int t = threadIdx.x;
  const int k0 = k4 * 72;

  const float* ibase = inp + (size_t)n * (196*32*17);
  for (int e = t; e < 72*16; e += 512) {
    int k = k0 + (e >> 4), h = e & 15;
    int kk = k >> 5, ci = k & 31;
    s_pose[e] = ibase[(((pr*2 + kk/3)*14 + (pc*2 + kk%3))*32 + ci)*17 + h];
  }
  if (t < 72) {
    int k = k0 + t; int kk = k >> 5, ci = k & 31;
    int i = kk/3, j = kk%3;
    int x = pr*2 + i, y = pc*2 + j;
    if (FIRST) {
      float a = ibase[((x*14 + y)*32 + ci)*17 + 16];
      s_ra[t] = a / (float)(covr(x) * covr(y) * OO);
    } else {
      float2 ms = msg[((size_t)n*169 + x*13 + y)*32 + ci];
      s_ra[t] = ms.x;   /* m  */
      s_s[t]  = ms.y;   /* act/(den+eps) */
    }
  }
  __syncthreads();

  const int o = t >> 4, h = t & 15, a = h >> 2, c = h & 3;
  const float* wp = wT + (o << 4) + (c << 2) + ((size_t)k0 << 9);
  const float* pp = s_pose + (a << 2);
  const float* zp = zzg + (size_t)np * KCO + ((size_t)k0 << 5) + o;

  float srr = 0.f, m1 = 0.f, m2 = 0.f;
#pragma unroll 8
  for (int k = 0; k < 72; ++k) {
    float rra;
    if (FIRST) rra = s_ra[k];
    else       rra = __expf(zp[(size_t)k << 5] - s_ra[k]) * s_s[k];
    float4 w4 = *(const float4*)(wp + ((size_t)k << 9));
    float4 p4 = *(const float4*)(pp + (k << 4));
    float v = p4.x*w4.x + p4.y*w4.y + p4.z*w4.z + p4.w*w4.w;
    srr += rra;
    float rv = rra * v;
    m1 += rv; m2 += rv * v;
  }
  float* pb = part + (size_t)blk * 1536 + t;
  pb[0] = srr; pb[512] = m1; pb[1024] = m2;
}

/* ---- K2: fused stats + zz. grid = 288np * 4k4, block 512 ---- */
template<int IT>
__global__ __launch_bounds__(512, 4) void zzstats_kernel(
    const float* __restrict__ inp, const float* __restrict__ wT,
    const float* __restrict__ part,
    const float* __restrict__ beta_v, const float* __restrict__ beta_a,
    float* __restrict__ zzg)
{
  __shared__ float s_pose[72*16];
  __shared__ float s_mean[512];
  __shared__ float s_i2v[512];
  __shared__ float s_cost[OO];
  __shared__ float s_lvs[OO];
  __shared__ float s_lc[OO];

  const int blk = blockIdx.x;
  const int np = blk >> 2, k4 = blk & 3;
  const int n = np / P2, p = np % P2;
  const int pr = p / PS, pc = p % PS;
  const int t = threadIdx.x;
  const int k0 = k4 * 72;

  const float* ibase = inp + (size_t)n * (196*32*17);
  for (int e = t; e < 72*16; e += 512) {
    int k = k0 + (e >> 4), h = e & 15;
    int kk = k >> 5, ci = k & 31;
    s_pose[e] = ibase[(((pr*2 + kk/3)*14 + (pc*2 + kk%3))*32 + ci)*17 + h];
  }

  /* ---- stats (redundant per k4, cheap): t = (o,h) ---- */
  {
    const int o = t >> 4;
    float rs = 0.f, a1 = 0.f, a2 = 0.f;
#pragma unroll
    for (int g = 0; g < 4; ++g) {
      const float* pb = part + (size_t)(np*4 + g) * 1536 + t;
      rs += pb[0]; a1 += pb[512]; a2 += pb[1024];
    }
    float S = rs + EPSF;
    float mean = a1 / S;
    float var  = fmaxf(a2 / S - mean*mean, 0.f) + EPSF;
    float lvh  = __logf(var);
    float ch   = (beta_v[o] + 0.5f * lvh) * rs;
    float lv   = lvh;
#pragma unroll
    for (int d = 1; d < 16; d <<= 1) {
      ch += __shfl_xor(ch, d, 64);
      lv += __shfl_xor(lv, d, 64);
    }
    s_mean[t] = mean;
    s_i2v[t]  = 0.5f / var;
    if ((t & 15) == 0) { s_cost[o] = ch; s_lvs[o] = lv; }
  }
  __syncthreads();

  if (t < OO) {
    float cm = 0.f;
#pragma unroll
    for (int oi = 0; oi < OO; ++oi) cm += s_cost[oi];
    cm *= (1.f / OO);
    float ssq = 0.f;
#pragma unroll
    for (int oi = 0; oi < OO; ++oi) { float d = s_cost[oi] - cm; ssq += d*d; }
    float sd = sqrtf(ssq * (1.f / OO));
    const float INVT = (IT==0) ? 5.0e-4f : 9.75e-4f;
    float arg = INVT * (beta_a[t] + (cm - s_cost[t]) / (sd + EPSF));
    float aj  = 1.f / (1.f + __expf(-arg));
    s_lc[t] = __logf(aj + EPSF) - 0.5f * (s_lvs[t] + 16.f * LOG2PI_F);
  }
  __syncthreads();

  const int o = t & 31;
  const float lc = s_lc[o];
  const float4* mo4 = (const float4*)(s_mean + (o<<4));
  const float4* io4 = (const float4*)(s_i2v  + (o<<4));
  float4 M0=mo4[0], M1=mo4[1], M2=mo4[2], M3=mo4[3];
  float4 I0=io4[0], I1=io4[1], I2=io4[2], I3=io4[3];

  float* zz = zzg + (size_t)np * KCO + ((size_t)k0 << 5);
#pragma unroll
  for (int it8 = 0; it8 < 5; ++it8) {
    int e = t + it8*512;
    if (e >= 2304) break;
    int k = e >> 5;
    const float4* wq = (const float4*)(wT + (((size_t)(k0 + k) << 5) + o) * 16);
    float4 w0=wq[0], w1=wq[1], w2=wq[2], w3=wq[3];
    const float4* pk4 = (const float4*)(s_pose + (k << 4));
    float ssum = 0.f;
    float4 Pa;
    Pa = pk4[0];
    {
      float x0 = Pa.x*w0.x + Pa.y*w0.y + Pa.z*w0.z + Pa.w*w0.w;
      float x1 = Pa.x*w1.x + Pa.y*w1.y + Pa.z*w1.z + Pa.w*w1.w;
      float x2 = Pa.x*w2.x + Pa.y*w2.y + Pa.z*w2.z + Pa.w*w2.w;
      float x3 = Pa.x*w3.x + Pa.y*w3.y + Pa.z*w3.z + Pa.w*w3.w;
      float d0=x0-M0.x, d1=x1-M0.y, d2=x2-M0.z, d3=x3-M0.w;
      ssum += d0*d0*I0.x + d1*d1*I0.y + d2*d2*I0.z + d3*d3*I0.w;
    }
    Pa = pk4[1];
    {
      float x0 = Pa.x*w0.x + Pa.y*w0.y + Pa.z*w0.z + Pa.w*w0.w;
      float x1 = Pa.x*w1.x + Pa.y*w1.y + Pa.z*w1.z + Pa.w*w1.w;
      float x2 = Pa.x*w2.x + Pa.y*w2.y + Pa.z*w2.z + Pa.w*w2.w;
      float x3 = Pa.x*w3.x + Pa.y*w3.y + Pa.z*w3.z + Pa.w*w3.w;
      float d0=x0-M1.x, d1=x1-M1.y, d2=x2-M1.z, d3=x3-M1.w;
      ssum += d0*d0*I1.x + d1*d1*I1.y + d2*d2*I1.z + d3*d3*I1.w;
    }
    Pa = pk4[2];
    {
      float x0 = Pa.x*w0.x + Pa.y*w0.y + Pa.z*w0.z + Pa.w*w0.w;
      float x1 = Pa.x*w1.x + Pa.y*w1.y + Pa.z*w1.z + Pa.w*w1.w;
      float x2 = Pa.x*w2.x + Pa.y*w2.y + Pa.z*w2.z + Pa.w*w2.w;
      float x3 = Pa.x*w3.x + Pa.y*w3.y + Pa.z*w3.z + Pa.w*w3.w;
      float d0=x0-M2.x, d1=x1-M2.y, d2=x2-M2.z, d3=x3-M2.w;
      ssum += d0*d0*I2.x + d1*d1*I2.y + d2*d2*I2.z + d3*d3*I2.w;
    }
    Pa = pk4[3];
    {
      float x0 = Pa.x*w0.x + Pa.y*w0.y + Pa.z*w0.z + Pa.w*w0.w;
      float x1 = Pa.x*w1.x + Pa.y*w1.y + Pa.z*w1.z + Pa.w*w1.w;
      float x2 = Pa.x*w2.x + Pa.y*w2.y + Pa.z*w2.z + Pa.w*w2.w;
      float x3 = Pa.x*w3.x + Pa.y*w3.y + Pa.z*w3.z + Pa.w*w3.w;
      float d0=x0-M3.x, d1=x1-M3.y, d2=x2-M3.z, d3=x3-M3.w;
      ssum += d0*d0*I3.x + d1*d1*I3.y + d2*d2*I3.z + d3*d3*I3.w;
    }
    zz[e] = lc - ssum;
  }
}

/* ---- K3: final stats -> output ---- */
__global__ __launch_bounds__(512) void statsout_kernel(
    const float* __restrict__ part,
    const float* __restrict__ beta_v, const float* __restrict__ beta_a,
    float* __restrict__ out)
{
  __shared__ float s_cost[OO];
  const int np = blockIdx.x;
  const int t = threadIdx.x;
  const int o = t >> 4, h = t & 15;

  float rs = 0.f, a1 = 0.f, a2 = 0.f;
#pragma unroll
  for (int g = 0; g < 4; ++g) {
    const float* pb = part + (size_t)(np*4 + g) * 1536 + t;
    rs += pb[0]; a1 += pb[512]; a2 += pb[1024];
  }
  float S = rs + EPSF;
  float mean = a1 / S;
  float var  = fmaxf(a2 / S - mean*mean, 0.f) + EPSF;
  float ch   = (beta_v[o] + 0.5f * __logf(var)) * rs;
#pragma unroll
  for (int d = 1; d < 16; d <<= 1) ch += __shfl_xor(ch, d, 64);
  if (h == 0) s_cost[o] = ch;
  __syncthreads();

  float cm = 0.f;
#pragma unroll
  for (int oi = 0; oi < OO; ++oi) cm += s_cost[oi];
  cm *= (1.f / OO);
  float ssq = 0.f;
#pragma unroll
  for (int oi = 0; oi < OO; ++oi) { float d = s_cost[oi] - cm; ssq += d*d; }
  float sd = sqrtf(ssq * (1.f / OO));
  float arg = 1.42625e-3f * (beta_a[o] + (cm - s_cost[o]) / (sd + EPSF));
  float aj  = 1.f / (1.f + __expf(-arg));

  out[((size_t)np*OO + o)*17 + 1 + h] = mean;
  if (h == 0) out[((size_t)np*OO + o)*17] = aj;
}

/* ---- childnorm: per-(child,ci) softmax stats; writes (m, act/den) ---- */
__device__ __forceinline__ float max8(const float* p, float m){
  const float4* z4 = (const float4*)p;
#pragma unroll
  for (int q=0;q<8;++q){ float4 v=z4[q]; m=fmaxf(m,fmaxf(fmaxf(v.x,v.y),fmaxf(v.z,v.w))); }
  return m;
}
__device__ __forceinline__ float sum8(const float* zp, float m, float den){
  const float4* z4=(const float4*)zp;
#pragma unroll
  for(int q=0;q<8;++q){ float4 v=z4[q];
    den += __expf(v.x-m)+__expf(v.y-m)+__expf(v.z-m)+__expf(v.w-m); }
  return den;
}

__global__ __launch_bounds__(128) void childnorm_kernel(
    const float* __restrict__ inp, const float* __restrict__ zzg,
    float2* __restrict__ msg)
{
  const int g = blockIdx.x * 128 + threadIdx.x;   /* 8*169*32 = 43264 */
  const int n   = g / (169*32);
  const int rem = g % (169*32);
  const int sc  = rem >> 5, ci = rem & 31;
  const int x = sc / 13, y = sc % 13;

  const float act = inp[(((size_t)n*196 + x*14 + y)*32 + ci)*17 + 16];

  int b0=-1,b1=-1,b2=-1,b3=-1; int np2=0;
#pragma unroll
  for (int r = 0; r < 6; ++r) {
    int i = x - 2*r;
    if (i < 0 || i > 2) continue;
#pragma unroll
    for (int c2 = 0; c2 < 6; ++c2) {
      int j = y - 2*c2;
      if (j < 0 || j > 2) continue;
      int base = (((n*P2 + r*6+c2)*9 + i*3+j)*CI + ci) << 5;
      if (np2==0) b0=base; else if (np2==1) b1=base; else if (np2==2) b2=base; else b3=base;
      ++np2;
    }
  }
  float m = -1e30f;
  if (b0>=0) m = max8(zzg+b0, m);
  if (b1>=0) m = max8(zzg+b1, m);
  if (b2>=0) m = max8(zzg+b2, m);
  if (b3>=0) m = max8(zzg+b3, m);
  float den = 0.f;
  if (b0>=0) den = sum8(zzg+b0, m, den);
  if (b1>=0) den = sum8(zzg+b1, m, den);
  if (b2>=0) den = sum8(zzg+b2, m, den);
  if (b3>=0) den = sum8(zzg+b3, m, den);
  float2 ms; ms.x = m; ms.y = act / (den + EPSF);
  msg[g] = ms;
}

extern "C" void kernel_launch(void* const* d_in, const int* in_sizes, int n_in,
                              void* d_out, int out_size, void* d_ws, size_t ws_size,
                              hipStream_t stream)
{
  (void)in_sizes; (void)n_in; (void)out_size; (void)ws_size;
  const float* inp = (const float*)d_in[0];
  const float* w   = (const float*)d_in[1];
  const float* bv  = (const float*)d_in[2];
  const float* ba  = (const float*)d_in[3];
  float* out = (float*)d_out;
  float* ws  = (float*)d_ws;
  float* zz   = ws + ZZ_OFF;
  float* part = ws + PART_OFF;
  float* wT   = ws + WT_OFF;
  float2* msg = (float2*)(ws + MS_OFF);

  wtrans_kernel<<<576, 256, 0, stream>>>(w, wT);

  moments_kernel<true ><<<1152, 512, 0, stream>>>(inp, wT, zz, msg, part);
  zzstats_kernel<0><<<1152, 512, 0, stream>>>(inp, wT, part, bv, ba, zz);
  childnorm_kernel<<<338, 128, 0, stream>>>(inp, zz, msg);

  moments_kernel<false><<<1152, 512, 0, stream>>>(inp, wT, zz, msg, part);
  zzstats_kernel<1><<<1152, 512, 0, stream>>>(inp, wT, part, bv, ba, zz);
  childnorm_kernel<<<338, 128, 0, stream>>>(inp, zz, msg);

  moments_kernel<false><<<1152, 512, 0, stream>>>(inp, wT, zz, msg, part);
  statsout_kernel<<<288, 512, 0, stream>>>(part, bv, ba, out);
}

// Round 5
// 159.654 us; speedup vs baseline: 1.4109x; 1.0019x over previous
//
#include <hip/hip_runtime.h>
#include <math.h>

#define PS 6
#define P2 36
#define CI 32
#define OO 32
#define KC 288
#define KCO 9216
#define EPSF 1e-9f
#define LOG2PI_F 1.8378770664093455f

/* workspace float offsets */
#define ZZ_OFF   0u            /* 2,654,208 floats */
#define RR_OFF   2654208u      /* 2,654,208 floats */
#define PART_OFF 5308416u      /* 1,769,472 floats */
#define WT_OFF   7077888u      /* 147,456 floats */

__device__ __forceinline__ int covr(int x){
  int cnt = 0;
#pragma unroll
  for (int r = 0; r < 6; ++r) { int i = x - 2*r; cnt += (i >= 0 && i <= 2) ? 1 : 0; }
  return cnt;
}

/* w[k][o][b][c] -> wT[k][o][c][b] */
__global__ __launch_bounds__(256) void wtrans_kernel(const float* __restrict__ w,
                                                     float* __restrict__ wT)
{
  int e = blockIdx.x * 256 + threadIdx.x;
  int ko = e >> 4, bc = e & 15;
  wT[(ko << 4) + ((bc & 3) << 2) + (bc >> 2)] = w[e];
}

/* ---- K1: partial moments. grid = 288np * 4k4, block 512 = (o,h) ---- */
template<bool FIRST>
__global__ __launch_bounds__(512, 8) void moments_kernel(
    const float* __restrict__ inp, const float* __restrict__ wT,
    const float* __restrict__ rrg, float* __restrict__ part)
{
  __shared__ float s_pose[72*16];
  __shared__ float s_ra[72];

  const int blk = blockIdx.x;
  const int np = blk >> 2, k4 = blk & 3;
  const int n = np / P2, p = np % P2;
  const int pr = p / PS, pc = p % PS;
  const int t = threadIdx.x;
  const int k0 = k4 * 72;

  const float* ibase = inp + (size_t)n * (196*32*17);
  for (int e = t; e < 72*16; e += 512) {
    int k = k0 + (e >> 4), h = e & 15;
    int kk = k >> 5, ci = k & 31;
    s_pose[e] = ibase[(((pr*2 + kk/3)*14 + (pc*2 + kk%3))*32 + ci)*17 + h];
  }
  if (FIRST && t < 72) {
    int k = k0 + t; int kk = k >> 5, ci = k & 31;
    int i = kk/3, j = kk%3;
    int x = pr*2 + i, y = pc*2 + j;
    float a = ibase[((x*14 + y)*32 + ci)*17 + 16];
    s_ra[t] = a / (float)(covr(x) * covr(y) * OO);
  }
  __syncthreads();

  const int o = t >> 4, h = t & 15, a = h >> 2, c = h & 3;
  const float* wp = wT + (o << 4) + (c << 2) + ((size_t)k0 << 9);
  const float* pp = s_pose + (a << 2);
  const float* rp = rrg + (size_t)np * KCO + ((size_t)k0 << 5) + o;

  float srr = 0.f, m1 = 0.f, m2 = 0.f;
#pragma unroll 4
  for (int k = 0; k < 72; ++k) {
    float rra = FIRST ? s_ra[k] : rp[(size_t)k << 5];
    float4 w4 = *(const float4*)(wp + ((size_t)k << 9));
    float4 p4 = *(const float4*)(pp + (k << 4));
    float v = p4.x*w4.x + p4.y*w4.y + p4.z*w4.z + p4.w*w4.w;
    srr += rra;
    float rv = rra * v;
    m1 += rv; m2 += rv * v;
  }
  float* pb = part + (size_t)blk * 1536 + t;
  pb[0] = srr; pb[512] = m1; pb[1024] = m2;
}

/* ---- K2: fused stats + zz. grid = 288np * 4k4, block 512 ---- */
template<int IT>
__global__ __launch_bounds__(512, 4) void zzstats_kernel(
    const float* __restrict__ inp, const float* __restrict__ wT,
    const float* __restrict__ part,
    const float* __restrict__ beta_v, const float* __restrict__ beta_a,
    float* __restrict__ zzg)
{
  __shared__ float s_pose[72*16];
  __shared__ float s_mean[512];
  __shared__ float s_i2v[512];
  __shared__ float s_cost[OO];
  __shared__ float s_lvs[OO];
  __shared__ float s_lc[OO];

  const int blk = blockIdx.x;
  const int np = blk >> 2, k4 = blk & 3;
  const int n = np / P2, p = np % P2;
  const int pr = p / PS, pc = p % PS;
  const int t = threadIdx.x;
  const int k0 = k4 * 72;

  const float* ibase = inp + (size_t)n * (196*32*17);
  for (int e = t; e < 72*16; e += 512) {
    int k = k0 + (e >> 4), h = e & 15;
    int kk = k >> 5, ci = k & 31;
    s_pose[e] = ibase[(((pr*2 + kk/3)*14 + (pc*2 + kk%3))*32 + ci)*17 + h];
  }

  {
    const int o = t >> 4;
    float rs = 0.f, a1 = 0.f, a2 = 0.f;
#pragma unroll
    for (int g = 0; g < 4; ++g) {
      const float* pb = part + (size_t)(np*4 + g) * 1536 + t;
      rs += pb[0]; a1 += pb[512]; a2 += pb[1024];
    }
    float S = rs + EPSF;
    float mean = a1 / S;
    float var  = fmaxf(a2 / S - mean*mean, 0.f) + EPSF;
    float lvh  = __logf(var);
    float ch   = (beta_v[o] + 0.5f * lvh) * rs;
    float lv   = lvh;
#pragma unroll
    for (int d = 1; d < 16; d <<= 1) {
      ch += __shfl_xor(ch, d, 64);
      lv += __shfl_xor(lv, d, 64);
    }
    s_mean[t] = mean;
    s_i2v[t]  = 0.5f / var;
    if ((t & 15) == 0) { s_cost[o] = ch; s_lvs[o] = lv; }
  }
  __syncthreads();

  if (t < OO) {
    float cm = 0.f;
#pragma unroll
    for (int oi = 0; oi < OO; ++oi) cm += s_cost[oi];
    cm *= (1.f / OO);
    float ssq = 0.f;
#pragma unroll
    for (int oi = 0; oi < OO; ++oi) { float d = s_cost[oi] - cm; ssq += d*d; }
    float sd = sqrtf(ssq * (1.f / OO));
    const float INVT = (IT==0) ? 5.0e-4f : 9.75e-4f;
    float arg = INVT * (beta_a[t] + (cm - s_cost[t]) / (sd + EPSF));
    float aj  = 1.f / (1.f + __expf(-arg));
    s_lc[t] = __logf(aj + EPSF) - 0.5f * (s_lvs[t] + 16.f * LOG2PI_F);
  }
  __syncthreads();

  const int o = t & 31;
  const float lc = s_lc[o];
  const float4* mo4 = (const float4*)(s_mean + (o<<4));
  const float4* io4 = (const float4*)(s_i2v  + (o<<4));
  float4 M0=mo4[0], M1=mo4[1], M2=mo4[2], M3=mo4[3];
  float4 I0=io4[0], I1=io4[1], I2=io4[2], I3=io4[3];

  float* zz = zzg + (size_t)np * KCO + ((size_t)k0 << 5);
#pragma unroll
  for (int it8 = 0; it8 < 5; ++it8) {
    int e = t + it8*512;
    if (e >= 2304) break;
    int k = e >> 5;
    const float4* wq = (const float4*)(wT + (((size_t)(k0 + k) << 5) + o) * 16);
    float4 w0=wq[0], w1=wq[1], w2=wq[2], w3=wq[3];
    const float4* pk4 = (const float4*)(s_pose + (k << 4));
    float ssum = 0.f;
    float4 Pa;
    Pa = pk4[0];
    {
      float x0 = Pa.x*w0.x + Pa.y*w0.y + Pa.z*w0.z + Pa.w*w0.w;
      float x1 = Pa.x*w1.x + Pa.y*w1.y + Pa.z*w1.z + Pa.w*w1.w;
      float x2 = Pa.x*w2.x + Pa.y*w2.y + Pa.z*w2.z + Pa.w*w2.w;
      float x3 = Pa.x*w3.x + Pa.y*w3.y + Pa.z*w3.z + Pa.w*w3.w;
      float d0=x0-M0.x, d1=x1-M0.y, d2=x2-M0.z, d3=x3-M0.w;
      ssum += d0*d0*I0.x + d1*d1*I0.y + d2*d2*I0.z + d3*d3*I0.w;
    }
    Pa = pk4[1];
    {
      float x0 = Pa.x*w0.x + Pa.y*w0.y + Pa.z*w0.z + Pa.w*w0.w;
      float x1 = Pa.x*w1.x + Pa.y*w1.y + Pa.z*w1.z + Pa.w*w1.w;
      float x2 = Pa.x*w2.x + Pa.y*w2.y + Pa.z*w2.z + Pa.w*w2.w;
      float x3 = Pa.x*w3.x + Pa.y*w3.y + Pa.z*w3.z + Pa.w*w3.w;
      float d0=x0-M1.x, d1=x1-M1.y, d2=x2-M1.z, d3=x3-M1.w;
      ssum += d0*d0*I1.x + d1*d1*I1.y + d2*d2*I1.z + d3*d3*I1.w;
    }
    Pa = pk4[2];
    {
      float x0 = Pa.x*w0.x + Pa.y*w0.y + Pa.z*w0.z + Pa.w*w0.w;
      float x1 = Pa.x*w1.x + Pa.y*w1.y + Pa.z*w1.z + Pa.w*w1.w;
      float x2 = Pa.x*w2.x + Pa.y*w2.y + Pa.z*w2.z + Pa.w*w2.w;
      float x3 = Pa.x*w3.x + Pa.y*w3.y + Pa.z*w3.z + Pa.w*w3.w;
      float d0=x0-M2.x, d1=x1-M2.y, d2=x2-M2.z, d3=x3-M2.w;
      ssum += d0*d0*I2.x + d1*d1*I2.y + d2*d2*I2.z + d3*d3*I2.w;
    }
    Pa = pk4[3];
    {
      float x0 = Pa.x*w0.x + Pa.y*w0.y + Pa.z*w0.z + Pa.w*w0.w;
      float x1 = Pa.x*w1.x + Pa.y*w1.y + Pa.z*w1.z + Pa.w*w1.w;
      float x2 = Pa.x*w2.x + Pa.y*w2.y + Pa.z*w2.z + Pa.w*w2.w;
      float x3 = Pa.x*w3.x + Pa.y*w3.y + Pa.z*w3.z + Pa.w*w3.w;
      float d0=x0-M3.x, d1=x1-M3.y, d2=x2-M3.z, d3=x3-M3.w;
      ssum += d0*d0*I3.x + d1*d1*I3.y + d2*d2*I3.z + d3*d3*I3.w;
    }
    zz[e] = lc - ssum;
  }
}

/* ---- K3: final stats -> output ---- */
__global__ __launch_bounds__(512) void statsout_kernel(
    const float* __restrict__ part,
    const float* __restrict__ beta_v, const float* __restrict__ beta_a,
    float* __restrict__ out)
{
  __shared__ float s_cost[OO];
  const int np = blockIdx.x;
  const int t = threadIdx.x;
  const int o = t >> 4, h = t & 15;

  float rs = 0.f, a1 = 0.f, a2 = 0.f;
#pragma unroll
  for (int g = 0; g < 4; ++g) {
    const float* pb = part + (size_t)(np*4 + g) * 1536 + t;
    rs += pb[0]; a1 += pb[512]; a2 += pb[1024];
  }
  float S = rs + EPSF;
  float mean = a1 / S;
  float var  = fmaxf(a2 / S - mean*mean, 0.f) + EPSF;
  float ch   = (beta_v[o] + 0.5f * __logf(var)) * rs;
#pragma unroll
  for (int d = 1; d < 16; d <<= 1) ch += __shfl_xor(ch, d, 64);
  if (h == 0) s_cost[o] = ch;
  __syncthreads();

  float cm = 0.f;
#pragma unroll
  for (int oi = 0; oi < OO; ++oi) cm += s_cost[oi];
  cm *= (1.f / OO);
  float ssq = 0.f;
#pragma unroll
  for (int oi = 0; oi < OO; ++oi) { float d = s_cost[oi] - cm; ssq += d*d; }
  float sd = sqrtf(ssq * (1.f / OO));
  float arg = 1.42625e-3f * (beta_a[o] + (cm - s_cost[o]) / (sd + EPSF));
  float aj  = 1.f / (1.f + __expf(-arg));

  out[((size_t)np*OO + o)*17 + 1 + h] = mean;
  if (h == 0) out[((size_t)np*OO + o)*17] = aj;
}

/* ---- childnorm: 4 parent-slots per (child,ci); writes rr = e*act/den ---- */
__global__ __launch_bounds__(256) void childnorm_kernel(
    const float* __restrict__ inp, const float* __restrict__ zzg,
    float* __restrict__ rrg)
{
  const int tg = blockIdx.x * 256 + threadIdx.x;   /* 43264*4 = 173056 */
  const int g = tg >> 2, slot = tg & 3;
  const int n   = g / (169*32);
  const int rem = g % (169*32);
  const int sc  = rem >> 5, ci = rem & 31;
  const int x = sc / 13, y = sc % 13;

  int base = -1; int cnt = 0;
#pragma unroll
  for (int r = 0; r < 6; ++r) {
    int i = x - 2*r;
    if (i < 0 || i > 2) continue;
#pragma unroll
    for (int c2 = 0; c2 < 6; ++c2) {
      int j = y - 2*c2;
      if (j < 0 || j > 2) continue;
      if (cnt == slot) base = (((n*P2 + r*6+c2)*9 + i*3+j)*CI + ci) << 5;
      ++cnt;
    }
  }

  const float4* z4 = (base >= 0) ? (const float4*)(zzg + base) : (const float4*)zzg;
  float4 zv[8];
#pragma unroll
  for (int q = 0; q < 8; ++q) zv[q] = z4[q];

  float m = -1e30f;
  if (base >= 0) {
#pragma unroll
    for (int q = 0; q < 8; ++q) {
      float4 v = zv[q];
      m = fmaxf(m, fmaxf(fmaxf(v.x, v.y), fmaxf(v.z, v.w)));
    }
  }
  m = fmaxf(m, __shfl_xor(m, 1, 64));
  m = fmaxf(m, __shfl_xor(m, 2, 64));

  float den = 0.f;
  float e[32];
  if (base >= 0) {
#pragma unroll
    for (int q = 0; q < 8; ++q) {
      float4 v = zv[q];
      e[q*4+0] = __expf(v.x - m); e[q*4+1] = __expf(v.y - m);
      e[q*4+2] = __expf(v.z - m); e[q*4+3] = __expf(v.w - m);
      den += e[q*4+0] + e[q*4+1] + e[q*4+2] + e[q*4+3];
    }
  }
  den += __shfl_xor(den, 1, 64);
  den += __shfl_xor(den, 2, 64);

  const float act = inp[(((size_t)n*196 + x*14 + y)*32 + ci)*17 + 16];
  float s = act / (den + EPSF);

  if (base >= 0) {
    float4* r4 = (float4*)(rrg + base);
#pragma unroll
    for (int q = 0; q < 8; ++q) {
      float4 rv;
      rv.x = e[q*4+0]*s; rv.y = e[q*4+1]*s; rv.z = e[q*4+2]*s; rv.w = e[q*4+3]*s;
      r4[q] = rv;
    }
  }
}

extern "C" void kernel_launch(void* const* d_in, const int* in_sizes, int n_in,
                              void* d_out, int out_size, void* d_ws, size_t ws_size,
                              hipStream_t stream)
{
  (void)in_sizes; (void)n_in; (void)out_size; (void)ws_size;
  const float* inp = (const float*)d_in[0];
  const float* w   = (const float*)d_in[1];
  const float* bv  = (const float*)d_in[2];
  const float* ba  = (const float*)d_in[3];
  float* out = (float*)d_out;
  float* ws  = (float*)d_ws;
  float* zz   = ws + ZZ_OFF;
  float* rr   = ws + RR_OFF;
  float* part = ws + PART_OFF;
  float* wT   = ws + WT_OFF;

  wtrans_kernel<<<576, 256, 0, stream>>>(w, wT);

  moments_kernel<true ><<<1152, 512, 0, stream>>>(inp, wT, rr, part);
  zzstats_kernel<0><<<1152, 512, 0, stream>>>(inp, wT, part, bv, ba, zz);
  childnorm_kernel<<<676, 256, 0, stream>>>(inp, zz, rr);

  moments_kernel<false><<<1152, 512, 0, stream>>>(inp, wT, rr, part);
  zzstats_kernel<1><<<1152, 512, 0, stream>>>(inp, wT, part, bv, ba, zz);
  childnorm_kernel<<<676, 256, 0, stream>>>(inp, zz, rr);

  moments_kernel<false><<<1152, 512, 0, stream>>>(inp, wT, rr, part);
  statsout_kernel<<<288, 512, 0, stream>>>(part, bv, ba, out);
}

// Round 6
// 135.740 us; speedup vs baseline: 1.6595x; 1.1762x over previous
//
#include <hip/hip_runtime.h>
#include <math.h>

#define PS 6
#define P2 36
#define CI 32
#define OO 32
#define KC 288
#define KCO 9216
#define EPSF 1e-9f
#define LOG2PI_F 1.8378770664093455f

/* workspace float offsets */
#define ZZ_OFF 0u            /* 2,654,208 floats */
#define RR_OFF 2654208u      /* 2,654,208 floats */
#define WT_OFF 5308416u      /* 147,456 floats */

__device__ __forceinline__ int covr(int x){
  int cnt = 0;
#pragma unroll
  for (int r = 0; r < 6; ++r) { int i = x - 2*r; cnt += (i >= 0 && i <= 2) ? 1 : 0; }
  return cnt;
}

/* wT[((k*4+c)*32+o)*4+b] = w[k][o][b][c] : per-(k,c) the 32 o-float4s are contiguous */
__global__ __launch_bounds__(256) void wtrans_kernel(const float* __restrict__ w,
                                                     float* __restrict__ wT)
{
  int e = blockIdx.x * 256 + threadIdx.x;   /* 147456 */
  int b = e & 3, o = (e >> 2) & 31, c = (e >> 7) & 3, k = e >> 9;
  wT[e] = w[k*512 + o*16 + b*4 + c];
}

/* ---- fused EM step: moments + stats + (zz | output). grid 288 = (n,p) ---- */
template<int IT>
__global__ __launch_bounds__(512, 2) void em_kernel(
    const float* __restrict__ inp, const float* __restrict__ wT,
    const float* __restrict__ rr,
    const float* __restrict__ beta_v, const float* __restrict__ beta_a,
    float* __restrict__ zzg, float* __restrict__ out)
{
  __shared__ float s_pose[KC*16];       /* 18.4 KB */
  __shared__ float s_red[8*32*33];      /* 33.8 KB */
  __shared__ float s_ra[(IT==0) ? KC : 4];
  __shared__ float s_mean[512];
  __shared__ float s_i2v[512];
  __shared__ float s_cost[OO];
  __shared__ float s_lvs[OO];
  __shared__ float s_lc[OO];

  const int np = blockIdx.x;
  const int n = np / P2, p = np % P2;
  const int pr = p / PS, pc = p % PS;
  const int t = threadIdx.x;

  /* P0: stage pose tile (+ act/ppc for IT 0) */
  const float* ibase = inp + (size_t)n * (196*32*17);
  for (int e = t; e < KC*16; e += 512) {
    int k = e >> 4, h = e & 15;
    int kk = k >> 5, ci = k & 31;
    s_pose[e] = ibase[(((pr*2 + kk/3)*14 + (pc*2 + kk%3))*32 + ci)*17 + h];
  }
  if (IT == 0 && t < KC) {
    int kk = t >> 5, ci = t & 31;
    int x = pr*2 + kk/3, y = pc*2 + kk%3;
    float a = ibase[((x*14 + y)*32 + ci)*17 + 16];
    s_ra[t] = a / (float)(covr(x) * covr(y) * OO);
  }
  __syncthreads();

  /* P1: moments — thread (ksub,o) owns full 16-vote rows for 18 k's */
  const int ksub = t >> 5, o = t & 31;
  float srr = 0.f;
  float m1[16], m2[16];
#pragma unroll
  for (int j = 0; j < 16; ++j) { m1[j] = 0.f; m2[j] = 0.f; }

  const float* rp = rr + (size_t)np * KCO;
#pragma unroll 2
  for (int ks = 0; ks < 18; ++ks) {
    int k = ksub*18 + ks;
    float rra = (IT == 0) ? s_ra[k] : rp[(k << 5) + o];
    const float4* pk  = (const float4*)s_pose + (k << 2);
    const float4* wkb = (const float4*)wT + (size_t)(k << 7) + o;
    float4 w0 = wkb[0], w1 = wkb[32], w2 = wkb[64], w3 = wkb[96];
    srr += rra;
#pragma unroll
    for (int a = 0; a < 4; ++a) {
      float4 P = pk[a];
      float v0 = P.x*w0.x + P.y*w0.y + P.z*w0.z + P.w*w0.w;
      float v1 = P.x*w1.x + P.y*w1.y + P.z*w1.z + P.w*w1.w;
      float v2 = P.x*w2.x + P.y*w2.y + P.z*w2.z + P.w*w2.w;
      float v3 = P.x*w3.x + P.y*w3.y + P.z*w3.z + P.w*w3.w;
      float r0 = rra*v0, r1 = rra*v1, r2 = rra*v2, r3 = rra*v3;
      m1[a*4+0] += r0;    m1[a*4+1] += r1;    m1[a*4+2] += r2;    m1[a*4+3] += r3;
      m2[a*4+0] += r0*v0; m2[a*4+1] += r1*v1; m2[a*4+2] += r2*v2; m2[a*4+3] += r3*v3;
    }
  }

  /* P2: reduce over 16 ksub: in-wave pair combine, then LDS across 8 waves */
  srr += __shfl_xor(srr, 32, 64);
#pragma unroll
  for (int j = 0; j < 16; ++j) {
    m1[j] += __shfl_xor(m1[j], 32, 64);
    m2[j] += __shfl_xor(m2[j], 32, 64);
  }
  {
    const int lane = t & 63, wv = t >> 6;
    if (lane < 32) {
      float* rb = s_red + (wv*32 + lane)*33;
      rb[0] = srr;
#pragma unroll
      for (int j = 0; j < 16; ++j) { rb[1+j] = m1[j]; rb[17+j] = m2[j]; }
    }
  }
  __syncthreads();
  for (int u = t; u < 1056; u += 512) {
    float s = 0.f;
#pragma unroll
    for (int wv = 0; wv < 8; ++wv) s += s_red[wv*1056 + u];
    s_red[u] = s;              /* safe: each u read/written by one thread */
  }
  __syncthreads();

  /* P3: stats: t = (so, h) */
  {
    const int so = t >> 4, h = t & 15;
    float rs = s_red[so*33];
    float a1 = s_red[so*33 + 1 + h];
    float a2 = s_red[so*33 + 17 + h];
    float S    = rs + EPSF;
    float mean = a1 / S;
    float var  = fmaxf(a2 / S - mean*mean, 0.f) + EPSF;
    float lvh  = __logf(var);
    float ch   = (beta_v[so] + 0.5f * lvh) * rs;
    float lv   = lvh;
#pragma unroll
    for (int d = 1; d < 16; d <<= 1) {
      ch += __shfl_xor(ch, d, 64);
      lv += __shfl_xor(lv, d, 64);
    }
    if (IT == 2) {
      out[((size_t)np*OO + so)*17 + 1 + h] = mean;
    } else {
      s_mean[t] = mean;
      s_i2v[t]  = 0.5f / var;
    }
    if (h == 0) { s_cost[so] = ch; s_lvs[so] = lv; }
  }
  __syncthreads();

  if (t < OO) {
    float cm = 0.f;
#pragma unroll
    for (int oi = 0; oi < OO; ++oi) cm += s_cost[oi];
    cm *= (1.f / OO);
    float ssq = 0.f;
#pragma unroll
    for (int oi = 0; oi < OO; ++oi) { float d = s_cost[oi] - cm; ssq += d*d; }
    float sd = sqrtf(ssq * (1.f / OO));
    const float INVT = (IT==0) ? 5.0e-4f : ((IT==1) ? 9.75e-4f : 1.42625e-3f);
    float arg = INVT * (beta_a[t] + (cm - s_cost[t]) / (sd + EPSF));
    float aj  = 1.f / (1.f + __expf(-arg));
    if (IT == 2) out[((size_t)np*OO + t)*17] = aj;
    else         s_lc[t] = __logf(aj + EPSF) - 0.5f * (s_lvs[t] + 16.f * LOG2PI_F);
  }
  if (IT == 2) return;
  __syncthreads();

  /* P4: zz — thread owns rows r = i*512+t, (k = r>>5, oz = r&31) */
  {
    const int oz = t & 31;
    const float lc = s_lc[oz];
    const float4* mo4 = (const float4*)(s_mean + (oz << 4));
    const float4* io4 = (const float4*)(s_i2v  + (oz << 4));
    float4 M0 = mo4[0], M1 = mo4[1], M2 = mo4[2], M3 = mo4[3];
    float4 I0 = io4[0], I1 = io4[1], I2 = io4[2], I3 = io4[3];
    float* zb = zzg + (size_t)np * KCO;
#pragma unroll 2
    for (int i = 0; i < 18; ++i) {
      int r = i*512 + t;
      int k = r >> 5;
      const float4* pk  = (const float4*)s_pose + (k << 2);
      const float4* wkb = (const float4*)wT + (size_t)(k << 7) + oz;
      float4 w0 = wkb[0], w1 = wkb[32], w2 = wkb[64], w3 = wkb[96];
      float ssum = 0.f;
      float4 P;
      P = pk[0];
      {
        float x0 = P.x*w0.x + P.y*w0.y + P.z*w0.z + P.w*w0.w;
        float x1 = P.x*w1.x + P.y*w1.y + P.z*w1.z + P.w*w1.w;
        float x2 = P.x*w2.x + P.y*w2.y + P.z*w2.z + P.w*w2.w;
        float x3 = P.x*w3.x + P.y*w3.y + P.z*w3.z + P.w*w3.w;
        float d0 = x0-M0.x, d1 = x1-M0.y, d2 = x2-M0.z, d3 = x3-M0.w;
        ssum += d0*d0*I0.x + d1*d1*I0.y + d2*d2*I0.z + d3*d3*I0.w;
      }
      P = pk[1];
      {
        float x0 = P.x*w0.x + P.y*w0.y + P.z*w0.z + P.w*w0.w;
        float x1 = P.x*w1.x + P.y*w1.y + P.z*w1.z + P.w*w1.w;
        float x2 = P.x*w2.x + P.y*w2.y + P.z*w2.z + P.w*w2.w;
        float x3 = P.x*w3.x + P.y*w3.y + P.z*w3.z + P.w*w3.w;
        float d0 = x0-M1.x, d1 = x1-M1.y, d2 = x2-M1.z, d3 = x3-M1.w;
        ssum += d0*d0*I1.x + d1*d1*I1.y + d2*d2*I1.z + d3*d3*I1.w;
      }
      P = pk[2];
      {
        float x0 = P.x*w0.x + P.y*w0.y + P.z*w0.z + P.w*w0.w;
        float x1 = P.x*w1.x + P.y*w1.y + P.z*w1.z + P.w*w1.w;
        float x2 = P.x*w2.x + P.y*w2.y + P.z*w2.z + P.w*w2.w;
        float x3 = P.x*w3.x + P.y*w3.y + P.z*w3.z + P.w*w3.w;
        float d0 = x0-M2.x, d1 = x1-M2.y, d2 = x2-M2.z, d3 = x3-M2.w;
        ssum += d0*d0*I2.x + d1*d1*I2.y + d2*d2*I2.z + d3*d3*I2.w;
      }
      P = pk[3];
      {
        float x0 = P.x*w0.x + P.y*w0.y + P.z*w0.z + P.w*w0.w;
        float x1 = P.x*w1.x + P.y*w1.y + P.z*w1.z + P.w*w1.w;
        float x2 = P.x*w2.x + P.y*w2.y + P.z*w2.z + P.w*w2.w;
        float x3 = P.x*w3.x + P.y*w3.y + P.z*w3.z + P.w*w3.w;
        float d0 = x0-M3.x, d1 = x1-M3.y, d2 = x2-M3.z, d3 = x3-M3.w;
        ssum += d0*d0*I3.x + d1*d1*I3.y + d2*d2*I3.z + d3*d3*I3.w;
      }
      zb[r] = lc - ssum;
    }
  }
}

/* ---- childnorm: 4 parent-slots per (child,ci); writes rr = e*act/den ---- */
__global__ __launch_bounds__(256) void childnorm_kernel(
    const float* __restrict__ inp, const float* __restrict__ zzg,
    float* __restrict__ rrg)
{
  const int tg = blockIdx.x * 256 + threadIdx.x;   /* 43264*4 = 173056 */
  const int g = tg >> 2, slot = tg & 3;
  const int n   = g / (169*32);
  const int rem = g % (169*32);
  const int sc  = rem >> 5, ci = rem & 31;
  const int x = sc / 13, y = sc % 13;

  int base = -1; int cnt = 0;
#pragma unroll
  for (int r = 0; r < 6; ++r) {
    int i = x - 2*r;
    if (i < 0 || i > 2) continue;
#pragma unroll
    for (int c2 = 0; c2 < 6; ++c2) {
      int j = y - 2*c2;
      if (j < 0 || j > 2) continue;
      if (cnt == slot) base = (((n*P2 + r*6+c2)*9 + i*3+j)*CI + ci) << 5;
      ++cnt;
    }
  }

  const float4* z4 = (base >= 0) ? (const float4*)(zzg + base) : (const float4*)zzg;
  float4 zv[8];
#pragma unroll
  for (int q = 0; q < 8; ++q) zv[q] = z4[q];

  float m = -1e30f;
  if (base >= 0) {
#pragma unroll
    for (int q = 0; q < 8; ++q) {
      float4 v = zv[q];
      m = fmaxf(m, fmaxf(fmaxf(v.x, v.y), fmaxf(v.z, v.w)));
    }
  }
  m = fmaxf(m, __shfl_xor(m, 1, 64));
  m = fmaxf(m, __shfl_xor(m, 2, 64));

  float den = 0.f;
  float e[32];
  if (base >= 0) {
#pragma unroll
    for (int q = 0; q < 8; ++q) {
      float4 v = zv[q];
      e[q*4+0] = __expf(v.x - m); e[q*4+1] = __expf(v.y - m);
      e[q*4+2] = __expf(v.z - m); e[q*4+3] = __expf(v.w - m);
      den += e[q*4+0] + e[q*4+1] + e[q*4+2] + e[q*4+3];
    }
  }
  den += __shfl_xor(den, 1, 64);
  den += __shfl_xor(den, 2, 64);

  const float act = inp[(((size_t)n*196 + x*14 + y)*32 + ci)*17 + 16];
  float s = act / (den + EPSF);

  if (base >= 0) {
    float4* r4 = (float4*)(rrg + base);
#pragma unroll
    for (int q = 0; q < 8; ++q) {
      float4 rv;
      rv.x = e[q*4+0]*s; rv.y = e[q*4+1]*s; rv.z = e[q*4+2]*s; rv.w = e[q*4+3]*s;
      r4[q] = rv;
    }
  }
}

extern "C" void kernel_launch(void* const* d_in, const int* in_sizes, int n_in,
                              void* d_out, int out_size, void* d_ws, size_t ws_size,
                              hipStream_t stream)
{
  (void)in_sizes; (void)n_in; (void)out_size; (void)ws_size;
  const float* inp = (const float*)d_in[0];
  const float* w   = (const float*)d_in[1];
  const float* bv  = (const float*)d_in[2];
  const float* ba  = (const float*)d_in[3];
  float* out = (float*)d_out;
  float* ws  = (float*)d_ws;
  float* zz  = ws + ZZ_OFF;
  float* rr  = ws + RR_OFF;
  float* wT  = ws + WT_OFF;

  wtrans_kernel<<<576, 256, 0, stream>>>(w, wT);

  em_kernel<0><<<288, 512, 0, stream>>>(inp, wT, rr, bv, ba, zz, out);
  childnorm_kernel<<<676, 256, 0, stream>>>(inp, zz, rr);
  em_kernel<1><<<288, 512, 0, stream>>>(inp, wT, rr, bv, ba, zz, out);
  childnorm_kernel<<<676, 256, 0, stream>>>(inp, zz, rr);
  em_kernel<2><<<288, 512, 0, stream>>>(inp, wT, rr, bv, ba, zz, out);
}

// Round 7
// 112.375 us; speedup vs baseline: 2.0045x; 1.2079x over previous
//
#include <hip/hip_runtime.h>
#include <math.h>

#define PS 6
#define P2 36
#define CI 32
#define OO 32
#define KC 288
#define KCO 9216
#define EPSF 1e-9f
#define LOG2PI_F 1.8378770664093455f

/* workspace float offsets */
#define ZZ_OFF   0u            /* 2,654,208 floats */
#define RR_OFF   2654208u      /* 2,654,208 floats */
#define WT_OFF   5308416u      /* 147,456 floats */
#define PART_OFF 5455872u      /* 1152*1056 = 1,216,512 floats */

__device__ __forceinline__ int covr(int x){
  int cnt = 0;
#pragma unroll
  for (int r = 0; r < 6; ++r) { int i = x - 2*r; cnt += (i >= 0 && i <= 2) ? 1 : 0; }
  return cnt;
}

/* wTr[((k*4+c)*32+o)*4+b] = w[k][o][b][c] */
__global__ __launch_bounds__(256) void wtrans_kernel(const float* __restrict__ w,
                                                     float* __restrict__ wT)
{
  int e = blockIdx.x * 256 + threadIdx.x;   /* 147456 */
  int b = e & 3, o = (e >> 2) & 31, c = (e >> 7) & 3, k = e >> 9;
  wT[e] = w[k*512 + o*16 + b*4 + c];
}

/* ---- K1: partial moments. grid = 1152 (np,k4), block 256 = (q,o) ---- */
template<bool FIRST>
__global__ __launch_bounds__(256, 5) void moments_kernel(
    const float* __restrict__ inp, const float* __restrict__ wT,
    const float* __restrict__ rrg, float* __restrict__ part)
{
  __shared__ float s_pose[72*16];
  __shared__ float s_ra[72];
  __shared__ float s_red[4*1056];

  const int blk = blockIdx.x;
  const int np = blk >> 2, k4 = blk & 3;
  const int n = np / P2, p = np % P2;
  const int pr = p / PS, pc = p % PS;
  const int t = threadIdx.x;
  const int k0 = k4 * 72;

  const float* ibase = inp + (size_t)n * (196*32*17);
  for (int e = t; e < 72*16; e += 256) {
    int kl = e >> 4, h = e & 15;
    int k = k0 + kl;
    int kk = k >> 5, ci = k & 31;
    s_pose[e] = ibase[(((pr*2 + kk/3)*14 + (pc*2 + kk%3))*32 + ci)*17 + h];
  }
  if (FIRST && t < 72) {
    int k = k0 + t; int kk = k >> 5, ci = k & 31;
    int x = pr*2 + kk/3, y = pc*2 + kk%3;
    float a = ibase[((x*14 + y)*32 + ci)*17 + 16];
    s_ra[t] = a / (float)(covr(x) * covr(y) * OO);
  }
  __syncthreads();

  const int q = t >> 5, o = t & 31;
  float srr = 0.f;
  float m1[16], m2[16];
#pragma unroll
  for (int j = 0; j < 16; ++j) { m1[j] = 0.f; m2[j] = 0.f; }

  const float* rp = rrg + (size_t)np * KCO;
#pragma unroll 3
  for (int ks = 0; ks < 9; ++ks) {
    int kl = q*9 + ks;
    int k  = k0 + kl;
    float rra = FIRST ? s_ra[kl] : rp[(k << 5) + o];
    const float4* pk  = (const float4*)s_pose + (kl << 2);
    const float4* wkb = (const float4*)wT + ((size_t)k << 7) + o;
    float4 w0 = wkb[0], w1 = wkb[32], w2 = wkb[64], w3 = wkb[96];
    srr += rra;
#pragma unroll
    for (int a = 0; a < 4; ++a) {
      float4 P = pk[a];
      float v0 = P.x*w0.x + P.y*w0.y + P.z*w0.z + P.w*w0.w;
      float v1 = P.x*w1.x + P.y*w1.y + P.z*w1.z + P.w*w1.w;
      float v2 = P.x*w2.x + P.y*w2.y + P.z*w2.z + P.w*w2.w;
      float v3 = P.x*w3.x + P.y*w3.y + P.z*w3.z + P.w*w3.w;
      float r0 = rra*v0, r1 = rra*v1, r2 = rra*v2, r3 = rra*v3;
      m1[a*4+0] += r0;    m1[a*4+1] += r1;    m1[a*4+2] += r2;    m1[a*4+3] += r3;
      m2[a*4+0] += r0*v0; m2[a*4+1] += r1*v1; m2[a*4+2] += r2*v2; m2[a*4+3] += r3*v3;
    }
  }

  /* combine q-pairs in-wave, then 4 wave-groups via LDS */
  srr += __shfl_xor(srr, 32, 64);
#pragma unroll
  for (int j = 0; j < 16; ++j) {
    m1[j] += __shfl_xor(m1[j], 32, 64);
    m2[j] += __shfl_xor(m2[j], 32, 64);
  }
  {
    const int lane = t & 63, wv = t >> 6;
    if (lane < 32) {
      float* rb = s_red + wv*1056 + lane*33;
      rb[0] = srr;
#pragma unroll
      for (int j = 0; j < 16; ++j) { rb[1+j] = m1[j]; rb[17+j] = m2[j]; }
    }
  }
  __syncthreads();
  float* pb = part + (size_t)blk * 1056;
  for (int u = t; u < 1056; u += 256) {
    float s = s_red[u] + s_red[1056+u] + s_red[2112+u] + s_red[3168+u];
    pb[u] = s;
  }
}

/* ---- K2: stats (redundant per k4) + zz. grid 1152, block 512 ---- */
template<int IT>
__global__ __launch_bounds__(512, 4) void zzstats_kernel(
    const float* __restrict__ inp, const float* __restrict__ wT,
    const float* __restrict__ part,
    const float* __restrict__ beta_v, const float* __restrict__ beta_a,
    float* __restrict__ zzg)
{
  __shared__ float s_pose[72*16];
  __shared__ float s_mean[512];
  __shared__ float s_i2v[512];
  __shared__ float s_cost[OO];
  __shared__ float s_lvs[OO];
  __shared__ float s_lc[OO];

  const int blk = blockIdx.x;
  const int np = blk >> 2, k4 = blk & 3;
  const int n = np / P2, p = np % P2;
  const int pr = p / PS, pc = p % PS;
  const int t = threadIdx.x;
  const int k0 = k4 * 72;

  const float* ibase = inp + (size_t)n * (196*32*17);
  for (int e = t; e < 72*16; e += 512) {
    int kl = e >> 4, h = e & 15;
    int k = k0 + kl;
    int kk = k >> 5, ci = k & 31;
    s_pose[e] = ibase[(((pr*2 + kk/3)*14 + (pc*2 + kk%3))*32 + ci)*17 + h];
  }

  /* stats: t = (so,h) */
  {
    const int so = t >> 4, h = t & 15;
    const float* pb = part + (size_t)np * 4224 + so*33;
    float rs = pb[0]        + pb[1056]        + pb[2112]        + pb[3168];
    float a1 = pb[1+h]      + pb[1056+1+h]    + pb[2112+1+h]    + pb[3168+1+h];
    float a2 = pb[17+h]     + pb[1056+17+h]   + pb[2112+17+h]   + pb[3168+17+h];
    float S    = rs + EPSF;
    float mean = a1 / S;
    float var  = fmaxf(a2 / S - mean*mean, 0.f) + EPSF;
    float lvh  = __logf(var);
    float ch   = (beta_v[so] + 0.5f * lvh) * rs;
    float lv   = lvh;
#pragma unroll
    for (int d = 1; d < 16; d <<= 1) {
      ch += __shfl_xor(ch, d, 64);
      lv += __shfl_xor(lv, d, 64);
    }
    s_mean[t] = mean;
    s_i2v[t]  = 0.5f / var;
    if (h == 0) { s_cost[so] = ch; s_lvs[so] = lv; }
  }
  __syncthreads();

  if (t < OO) {
    float cm = 0.f;
#pragma unroll
    for (int oi = 0; oi < OO; ++oi) cm += s_cost[oi];
    cm *= (1.f / OO);
    float ssq = 0.f;
#pragma unroll
    for (int oi = 0; oi < OO; ++oi) { float d = s_cost[oi] - cm; ssq += d*d; }
    float sd = sqrtf(ssq * (1.f / OO));
    const float INVT = (IT==0) ? 5.0e-4f : 9.75e-4f;
    float arg = INVT * (beta_a[t] + (cm - s_cost[t]) / (sd + EPSF));
    float aj  = 1.f / (1.f + __expf(-arg));
    s_lc[t] = __logf(aj + EPSF) - 0.5f * (s_lvs[t] + 16.f * LOG2PI_F);
  }
  __syncthreads();

  /* zz rows r = k_local*32 + oz */
  {
    const int oz = t & 31;
    const float lc = s_lc[oz];
    const float4* mo4 = (const float4*)(s_mean + (oz << 4));
    const float4* io4 = (const float4*)(s_i2v  + (oz << 4));
    float4 M0 = mo4[0], M1 = mo4[1], M2 = mo4[2], M3 = mo4[3];
    float4 I0 = io4[0], I1 = io4[1], I2 = io4[2], I3 = io4[3];
    float* zb = zzg + (size_t)np * KCO + ((size_t)k0 << 5);
    for (int r = t; r < 2304; r += 512) {
      int kl = r >> 5;
      int k  = k0 + kl;
      const float4* pk  = (const float4*)s_pose + (kl << 2);
      const float4* wkb = (const float4*)wT + ((size_t)k << 7) + oz;
      float4 w0 = wkb[0], w1 = wkb[32], w2 = wkb[64], w3 = wkb[96];
      float ssum = 0.f;
      float4 P;
      P = pk[0];
      {
        float x0 = P.x*w0.x + P.y*w0.y + P.z*w0.z + P.w*w0.w;
        float x1 = P.x*w1.x + P.y*w1.y + P.z*w1.z + P.w*w1.w;
        float x2 = P.x*w2.x + P.y*w2.y + P.z*w2.z + P.w*w2.w;
        float x3 = P.x*w3.x + P.y*w3.y + P.z*w3.z + P.w*w3.w;
        float d0 = x0-M0.x, d1 = x1-M0.y, d2 = x2-M0.z, d3 = x3-M0.w;
        ssum += d0*d0*I0.x + d1*d1*I0.y + d2*d2*I0.z + d3*d3*I0.w;
      }
      P = pk[1];
      {
        float x0 = P.x*w0.x + P.y*w0.y + P.z*w0.z + P.w*w0.w;
        float x1 = P.x*w1.x + P.y*w1.y + P.z*w1.z + P.w*w1.w;
        float x2 = P.x*w2.x + P.y*w2.y + P.z*w2.z + P.w*w2.w;
        float x3 = P.x*w3.x + P.y*w3.y + P.z*w3.z + P.w*w3.w;
        float d0 = x0-M1.x, d1 = x1-M1.y, d2 = x2-M1.z, d3 = x3-M1.w;
        ssum += d0*d0*I1.x + d1*d1*I1.y + d2*d2*I1.z + d3*d3*I1.w;
      }
      P = pk[2];
      {
        float x0 = P.x*w0.x + P.y*w0.y + P.z*w0.z + P.w*w0.w;
        float x1 = P.x*w1.x + P.y*w1.y + P.z*w1.z + P.w*w1.w;
        float x2 = P.x*w2.x + P.y*w2.y + P.z*w2.z + P.w*w2.w;
        float x3 = P.x*w3.x + P.y*w3.y + P.z*w3.z + P.w*w3.w;
        float d0 = x0-M2.x, d1 = x1-M2.y, d2 = x2-M2.z, d3 = x3-M2.w;
        ssum += d0*d0*I2.x + d1*d1*I2.y + d2*d2*I2.z + d3*d3*I2.w;
      }
      P = pk[3];
      {
        float x0 = P.x*w0.x + P.y*w0.y + P.z*w0.z + P.w*w0.w;
        float x1 = P.x*w1.x + P.y*w1.y + P.z*w1.z + P.w*w1.w;
        float x2 = P.x*w2.x + P.y*w2.y + P.z*w2.z + P.w*w2.w;
        float x3 = P.x*w3.x + P.y*w3.y + P.z*w3.z + P.w*w3.w;
        float d0 = x0-M3.x, d1 = x1-M3.y, d2 = x2-M3.z, d3 = x3-M3.w;
        ssum += d0*d0*I3.x + d1*d1*I3.y + d2*d2*I3.z + d3*d3*I3.w;
      }
      zb[r] = lc - ssum;
    }
  }
}

/* ---- K3: final stats -> output. grid 288, block 512 ---- */
__global__ __launch_bounds__(512) void statsout_kernel(
    const float* __restrict__ part,
    const float* __restrict__ beta_v, const float* __restrict__ beta_a,
    float* __restrict__ out)
{
  __shared__ float s_cost[OO];
  const int np = blockIdx.x;
  const int t = threadIdx.x;
  const int o = t >> 4, h = t & 15;

  const float* pb = part + (size_t)np * 4224 + o*33;
  float rs = pb[0]    + pb[1056]      + pb[2112]      + pb[3168];
  float a1 = pb[1+h]  + pb[1056+1+h]  + pb[2112+1+h]  + pb[3168+1+h];
  float a2 = pb[17+h] + pb[1056+17+h] + pb[2112+17+h] + pb[3168+17+h];
  float S = rs + EPSF;
  float mean = a1 / S;
  float var  = fmaxf(a2 / S - mean*mean, 0.f) + EPSF;
  float ch   = (beta_v[o] + 0.5f * __logf(var)) * rs;
#pragma unroll
  for (int d = 1; d < 16; d <<= 1) ch += __shfl_xor(ch, d, 64);
  if (h == 0) s_cost[o] = ch;
  __syncthreads();

  float cm = 0.f;
#pragma unroll
  for (int oi = 0; oi < OO; ++oi) cm += s_cost[oi];
  cm *= (1.f / OO);
  float ssq = 0.f;
#pragma unroll
  for (int oi = 0; oi < OO; ++oi) { float d = s_cost[oi] - cm; ssq += d*d; }
  float sd = sqrtf(ssq * (1.f / OO));
  float arg = 1.42625e-3f * (beta_a[o] + (cm - s_cost[o]) / (sd + EPSF));
  float aj  = 1.f / (1.f + __expf(-arg));

  out[((size_t)np*OO + o)*17 + 1 + h] = mean;
  if (h == 0) out[((size_t)np*OO + o)*17] = aj;
}

/* ---- childnorm: 4 parent-slots per (child,ci); writes rr = e*act/den ---- */
__global__ __launch_bounds__(256) void childnorm_kernel(
    const float* __restrict__ inp, const float* __restrict__ zzg,
    float* __restrict__ rrg)
{
  const int tg = blockIdx.x * 256 + threadIdx.x;   /* 43264*4 = 173056 */
  const int g = tg >> 2, slot = tg & 3;
  const int n   = g / (169*32);
  const int rem = g % (169*32);
  const int sc  = rem >> 5, ci = rem & 31;
  const int x = sc / 13, y = sc % 13;

  int base = -1; int cnt = 0;
#pragma unroll
  for (int r = 0; r < 6; ++r) {
    int i = x - 2*r;
    if (i < 0 || i > 2) continue;
#pragma unroll
    for (int c2 = 0; c2 < 6; ++c2) {
      int j = y - 2*c2;
      if (j < 0 || j > 2) continue;
      if (cnt == slot) base = (((n*P2 + r*6+c2)*9 + i*3+j)*CI + ci) << 5;
      ++cnt;
    }
  }

  const float4* z4 = (base >= 0) ? (const float4*)(zzg + base) : (const float4*)zzg;
  float4 zv[8];
#pragma unroll
  for (int q = 0; q < 8; ++q) zv[q] = z4[q];

  float m = -1e30f;
  if (base >= 0) {
#pragma unroll
    for (int q = 0; q < 8; ++q) {
      float4 v = zv[q];
      m = fmaxf(m, fmaxf(fmaxf(v.x, v.y), fmaxf(v.z, v.w)));
    }
  }
  m = fmaxf(m, __shfl_xor(m, 1, 64));
  m = fmaxf(m, __shfl_xor(m, 2, 64));

  float den = 0.f;
  float e[32];
  if (base >= 0) {
#pragma unroll
    for (int q = 0; q < 8; ++q) {
      float4 v = zv[q];
      e[q*4+0] = __expf(v.x - m); e[q*4+1] = __expf(v.y - m);
      e[q*4+2] = __expf(v.z - m); e[q*4+3] = __expf(v.w - m);
      den += e[q*4+0] + e[q*4+1] + e[q*4+2] + e[q*4+3];
    }
  }
  den += __shfl_xor(den, 1, 64);
  den += __shfl_xor(den, 2, 64);

  const float act = inp[(((size_t)n*196 + x*14 + y)*32 + ci)*17 + 16];
  float s = act / (den + EPSF);

  if (base >= 0) {
    float4* r4 = (float4*)(rrg + base);
#pragma unroll
    for (int q = 0; q < 8; ++q) {
      float4 rv;
      rv.x = e[q*4+0]*s; rv.y = e[q*4+1]*s; rv.z = e[q*4+2]*s; rv.w = e[q*4+3]*s;
      r4[q] = rv;
    }
  }
}

extern "C" void kernel_launch(void* const* d_in, const int* in_sizes, int n_in,
                              void* d_out, int out_size, void* d_ws, size_t ws_size,
                              hipStream_t stream)
{
  (void)in_sizes; (void)n_in; (void)out_size; (void)ws_size;
  const float* inp = (const float*)d_in[0];
  const float* w   = (const float*)d_in[1];
  const float* bv  = (const float*)d_in[2];
  const float* ba  = (const float*)d_in[3];
  float* out = (float*)d_out;
  float* ws  = (float*)d_ws;
  float* zz   = ws + ZZ_OFF;
  float* rr   = ws + RR_OFF;
  float* wT   = ws + WT_OFF;
  float* part = ws + PART_OFF;

  wtrans_kernel<<<576, 256, 0, stream>>>(w, wT);

  moments_kernel<true ><<<1152, 256, 0, stream>>>(inp, wT, rr, part);
  zzstats_kernel<0><<<1152, 512, 0, stream>>>(inp, wT, part, bv, ba, zz);
  childnorm_kernel<<<676, 256, 0, stream>>>(inp, zz, rr);

  moments_kernel<false><<<1152, 256, 0, stream>>>(inp, wT, rr, part);
  zzstats_kernel<1><<<1152, 512, 0, stream>>>(inp, wT, part, bv, ba, zz);
  childnorm_kernel<<<676, 256, 0, stream>>>(inp, zz, rr);

  moments_kernel<false><<<1152, 256, 0, stream>>>(inp, wT, rr, part);
  statsout_kernel<<<288, 512, 0, stream>>>(part, bv, ba, out);
}